// Round 2
// baseline (2794.273 us; speedup 1.0000x reference)
//
#include <hip/hip_runtime.h>
#include <math.h>

// Problem constants
#define B_   4
#define N_   2048
#define D_   1024
#define H_   16
#define d_   64
#define F_   2048
#define PAD_ 8192
#define FB_  4097
#define NC_  32
#define EPS_ 1e-6f
#define PI_F 3.14159265358979323846f

// ---------------------------------------------------------------------------
// Generic fp32 NT GEMM: C[m,n] = act( sum_k A[m,k]*B[n,k] + bias[n] )
// act: 0 = none, 1 = gelu(tanh approx). A has leading dim lda (>= K).
// BM=BN=64, BK=16, 256 threads, 4x4 microtile.
// ---------------------------------------------------------------------------
__device__ __forceinline__ float gelu_f(float x) {
    return 0.5f * x * (1.f + tanhf(0.7978845608028654f * (x + 0.044715f * x * x * x)));
}

__global__ __launch_bounds__(256) void gemm_nt(const float* __restrict__ A,
                                               const float* __restrict__ Bm,
                                               const float* __restrict__ bias,
                                               float* __restrict__ C,
                                               int M, int Nn, int K, int lda, int act) {
    __shared__ float As[16][64];
    __shared__ float Bs[16][64];
    const int tid = threadIdx.x;
    const int tx = tid & 15, ty = tid >> 4;
    const int m0 = blockIdx.y * 64, n0 = blockIdx.x * 64;

    float acc[4][4];
#pragma unroll
    for (int i = 0; i < 4; ++i)
#pragma unroll
        for (int j = 0; j < 4; ++j) acc[i][j] = 0.f;

    const int lr = tid >> 2;           // 0..63 row within tile
    const int lk = (tid & 3) * 4;      // 0,4,8,12 col group

    for (int k0 = 0; k0 < K; k0 += 16) {
        float4 av = make_float4(0.f, 0.f, 0.f, 0.f);
        float4 bv = make_float4(0.f, 0.f, 0.f, 0.f);
        if (m0 + lr < M)
            av = *(const float4*)(A + (size_t)(m0 + lr) * lda + k0 + lk);
        if (n0 + lr < Nn)
            bv = *(const float4*)(Bm + (size_t)(n0 + lr) * K + k0 + lk);
        As[lk + 0][lr] = av.x; As[lk + 1][lr] = av.y;
        As[lk + 2][lr] = av.z; As[lk + 3][lr] = av.w;
        Bs[lk + 0][lr] = bv.x; Bs[lk + 1][lr] = bv.y;
        Bs[lk + 2][lr] = bv.z; Bs[lk + 3][lr] = bv.w;
        __syncthreads();
#pragma unroll
        for (int k = 0; k < 16; ++k) {
            float a[4], b[4];
#pragma unroll
            for (int i = 0; i < 4; ++i) a[i] = As[k][ty * 4 + i];
#pragma unroll
            for (int j = 0; j < 4; ++j) b[j] = Bs[k][tx * 4 + j];
#pragma unroll
            for (int i = 0; i < 4; ++i)
#pragma unroll
                for (int j = 0; j < 4; ++j) acc[i][j] += a[i] * b[j];
        }
        __syncthreads();
    }
#pragma unroll
    for (int i = 0; i < 4; ++i) {
        int row = m0 + ty * 4 + i;
        if (row >= M) continue;
#pragma unroll
        for (int j = 0; j < 4; ++j) {
            int col = n0 + tx * 4 + j;
            if (col >= Nn) continue;
            float v = acc[i][j] + bias[col];
            if (act == 1) v = gelu_f(v);
            C[(size_t)row * Nn + col] = v;
        }
    }
}

// ---------------------------------------------------------------------------
// Featuremap + field build. One block = (b, h, 64-token slab). 256 threads.
// K path FIRST (builds wg, phi_k, field rows), then Q path which writes
// phi_q INTO qkvg's k-columns (those k values belong to this (b,h,slab) and
// are already consumed). field layout: field[(b*H+h)*128 + c][f].
// frac == 0 scatter: token 2047 folds into slot 2046, slot 2047 = 0.
// ---------------------------------------------------------------------------
__global__ __launch_bounds__(256) void kern_feat(float* __restrict__ qkvg,
                                                 const float* __restrict__ qfm_w,
                                                 const float* __restrict__ qfm_b,
                                                 const float* __restrict__ kfm_w,
                                                 const float* __restrict__ kfm_b,
                                                 const float* __restrict__ wg_w,
                                                 const float* __restrict__ wg_b,
                                                 float* __restrict__ field) {
    __shared__ float in_t[64][65];
    __shared__ float tmp[64][65];
    __shared__ float wbuf[64][65];
    __shared__ float bsm[64];
    __shared__ float wsm[64];
    __shared__ float wgbuf[64];

    const int tid = threadIdx.x;
    const int lane = tid & 63, grp = tid >> 6;
    const int n0 = blockIdx.x * 64;
    const int h = blockIdx.y, b = blockIdx.z;
    const size_t rowbase = (size_t)(b * N_ + n0) * 4096;

    // ============ K path ============
    for (int it = 0; it < 16; ++it) {
        int i = grp + 4 * it;
        in_t[i][lane] = qkvg[rowbase + (size_t)i * 4096 + D_ + h * 64 + lane];
    }
    for (int it = 0; it < 16; ++it) {
        int r = grp + 4 * it;
        wbuf[lane][r] = kfm_w[(size_t)r * 64 + lane];   // wbuf[c][j] = W0[j][c]
    }
    if (tid < 64) { bsm[tid] = kfm_b[tid]; wsm[tid] = wg_w[tid]; }
    __syncthreads();
    if (tid < 64) {   // wg from raw k
        float s = 0.f;
        for (int c = 0; c < 64; ++c) s += in_t[tid][c] * wsm[c];
        s += wg_b[0];
        wgbuf[tid] = 1.f / (1.f + expf(-s));
    }
    {   // L1: tmp = relu(in @ W0^T + b0)
        const int j = lane, ibase = grp * 16;
        float acc[16];
#pragma unroll
        for (int ii = 0; ii < 16; ++ii) acc[ii] = 0.f;
        for (int c = 0; c < 64; ++c) {
            float w = wbuf[c][j];
#pragma unroll
            for (int ii = 0; ii < 16; ++ii) acc[ii] += in_t[ibase + ii][c] * w;
        }
        float bj = bsm[j];
#pragma unroll
        for (int ii = 0; ii < 16; ++ii) tmp[ibase + ii][j] = fmaxf(acc[ii] + bj, 0.f);
    }
    __syncthreads();
    for (int it = 0; it < 16; ++it) {
        int r = grp + 4 * it;
        wbuf[lane][r] = kfm_w[(size_t)(64 + r) * 64 + lane];
    }
    if (tid < 64) bsm[tid] = kfm_b[64 + tid];
    __syncthreads();
    {   // L2: phi_k -> in_t (overwrites raw k in LDS)
        const int j = lane, ibase = grp * 16;
        float acc[16];
#pragma unroll
        for (int ii = 0; ii < 16; ++ii) acc[ii] = 0.f;
        for (int c = 0; c < 64; ++c) {
            float w = wbuf[c][j];
#pragma unroll
            for (int ii = 0; ii < 16; ++ii) acc[ii] += tmp[ibase + ii][c] * w;
        }
        float bj = bsm[j];
#pragma unroll
        for (int ii = 0; ii < 16; ++ii)
            in_t[ibase + ii][j] = fmaxf(acc[ii] + bj, 0.f) + EPS_;
    }
    __syncthreads();
    for (int it = 0; it < 16; ++it) {   // V -> tmp
        int i = grp + 4 * it;
        tmp[i][lane] = qkvg[rowbase + (size_t)i * 4096 + 2 * D_ + h * 64 + lane];
    }
    __syncthreads();

    // field write: write[c<64] = wg*pk*v ; write[c>=64] = wg*pk
    {
        float* frow = field + (size_t)(b * H_ + h) * 128 * F_;
        const bool last = (n0 == N_ - 64);
        for (int c = grp; c < 128; c += 4) {
            int i = lane;
            float v = (c < 64) ? wgbuf[i] * in_t[i][c] * tmp[i][c]
                               : wgbuf[i] * in_t[i][c - 64];
            if (last) {
                if (i == 62) {
                    float v2 = (c < 64) ? wgbuf[63] * in_t[63][c] * tmp[63][c]
                                        : wgbuf[63] * in_t[63][c - 64];
                    v += v2;              // token 2047 folds into slot 2046
                } else if (i == 63) v = 0.f;   // slot 2047 receives nothing
            }
            frow[(size_t)c * F_ + n0 + i] = v;
        }
    }
    __syncthreads();

    // ============ Q path ============
    for (int it = 0; it < 16; ++it) {
        int i = grp + 4 * it;
        in_t[i][lane] = qkvg[rowbase + (size_t)i * 4096 + h * 64 + lane];
    }
    for (int it = 0; it < 16; ++it) {
        int r = grp + 4 * it;
        wbuf[lane][r] = qfm_w[(size_t)r * 64 + lane];
    }
    if (tid < 64) bsm[tid] = qfm_b[tid];
    __syncthreads();
    {   // L1
        const int j = lane, ibase = grp * 16;
        float acc[16];
#pragma unroll
        for (int ii = 0; ii < 16; ++ii) acc[ii] = 0.f;
        for (int c = 0; c < 64; ++c) {
            float w = wbuf[c][j];
#pragma unroll
            for (int ii = 0; ii < 16; ++ii) acc[ii] += in_t[ibase + ii][c] * w;
        }
        float bj = bsm[j];
#pragma unroll
        for (int ii = 0; ii < 16; ++ii) tmp[ibase + ii][j] = fmaxf(acc[ii] + bj, 0.f);
    }
    __syncthreads();
    for (int it = 0; it < 16; ++it) {
        int r = grp + 4 * it;
        wbuf[lane][r] = qfm_w[(size_t)(64 + r) * 64 + lane];
    }
    if (tid < 64) bsm[tid] = qfm_b[64 + tid];
    __syncthreads();
    {   // L2: phi_q -> qkvg k-columns (this block's own, already-consumed k)
        const int j = lane, ibase = grp * 16;
        float acc[16];
#pragma unroll
        for (int ii = 0; ii < 16; ++ii) acc[ii] = 0.f;
        for (int c = 0; c < 64; ++c) {
            float w = wbuf[c][j];
#pragma unroll
            for (int ii = 0; ii < 16; ++ii) acc[ii] += tmp[ibase + ii][c] * w;
        }
        float bj = bsm[j];
#pragma unroll
        for (int ii = 0; ii < 16; ++ii) {
            float v = fmaxf(acc[ii] + bj, 0.f) + EPS_;
            qkvg[rowbase + (size_t)(ibase + ii) * 4096 + D_ + h * 64 + j] = v;
        }
    }
}

// ---------------------------------------------------------------------------
// LayerNorm of q token 0 -> q0n (B x 1024). One 64-thread block per (b,h).
// ---------------------------------------------------------------------------
__global__ void kern_ln(const float* __restrict__ qkvg,
                        const float* __restrict__ ln_g,
                        const float* __restrict__ ln_b,
                        float* __restrict__ q0n) {
    const int bh = blockIdx.x, c = threadIdx.x;
    const int b = bh >> 4, h = bh & 15;
    float x = qkvg[(size_t)(b * N_) * 4096 + h * 64 + c];
    float mu = x;
    for (int m = 1; m < 64; m <<= 1) mu += __shfl_xor(mu, m);
    mu *= (1.f / 64.f);
    float dv = (x - mu) * (x - mu);
    for (int m = 1; m < 64; m <<= 1) dv += __shfl_xor(dv, m);
    float var = dv * (1.f / 64.f);
    q0n[b * 1024 + h * 64 + c] = (x - mu) * rsqrtf(var + 1e-5f) * ln_g[c] + ln_b[c];
}

// ---------------------------------------------------------------------------
// Radix-2 FFT helpers on LDS (length 8192, 256 threads).
// DIF forward: natural in -> bit-reversed out.   DIT inverse: BR in -> natural out.
// ---------------------------------------------------------------------------
__device__ __forceinline__ void fft_fwd_dif(float* xr, float* xi, int tid) {
    for (int s = 0; s < 13; ++s) {
        const int lh = 12 - s;
        const int hh = 1 << lh;
        for (int t = tid; t < 4096; t += 256) {
            int j = t & (hh - 1);
            int i1 = ((t >> lh) << (lh + 1)) | j;
            int i2 = i1 + hh;
            float ar = xr[i1], ai = xi[i1];
            float br = xr[i2], bi = xi[i2];
            xr[i1] = ar + br; xi[i1] = ai + bi;
            float tr = ar - br, ti = ai - bi;
            float ang = -PI_F * (float)j / (float)hh;
            float sn, cs; __sincosf(ang, &sn, &cs);
            xr[i2] = tr * cs - ti * sn;
            xi[i2] = tr * sn + ti * cs;
        }
        __syncthreads();
    }
}

__device__ __forceinline__ void fft_inv_dit(float* xr, float* xi, int tid) {
    for (int s = 0; s < 13; ++s) {
        const int lh = s;
        const int hh = 1 << lh;
        for (int t = tid; t < 4096; t += 256) {
            int j = t & (hh - 1);
            int i1 = ((t >> lh) << (lh + 1)) | j;
            int i2 = i1 + hh;
            float ang = PI_F * (float)j / (float)hh;
            float sn, cs; __sincosf(ang, &sn, &cs);
            float br = xr[i2], bi = xi[i2];
            float tr = br * cs - bi * sn;
            float ti = br * sn + bi * cs;
            float ar = xr[i1], ai = xi[i1];
            xr[i1] = ar + tr; xi[i1] = ai + ti;
            xr[i2] = ar - tr; xi[i2] = ar == ar ? ai - ti : ai - ti;
        }
        __syncthreads();
    }
}

// base spectrum (bit-reversed order) of the damped-cosine kernel, per head
__global__ __launch_bounds__(256) void kern_base_fft(const float* __restrict__ freq,
                                                     const float* __restrict__ damp,
                                                     const float* __restrict__ phase,
                                                     float* __restrict__ baseBR) {
    __shared__ float xr[PAD_];
    __shared__ float xi[PAD_];
    const int h = blockIdx.x, tid = threadIdx.x;
    const float fr = freq[h], ed = expf(damp[h]), ph = phase[h];
    for (int f = tid; f < PAD_; f += 256) {
        float v = 0.f;
        if (f < F_) {
            float t = (float)f / (float)F_;
            v = expf(-ed * t) * cosf(fr * t + ph);
        }
        xr[f] = v; xi[f] = 0.f;
    }
    __syncthreads();
    fft_fwd_dif(xr, xi, tid);
    for (int j = tid; j < PAD_; j += 256) {
        baseBR[(size_t)(h * PAD_ + j) * 2 + 0] = xr[j];
        baseBR[(size_t)(h * PAD_ + j) * 2 + 1] = xi[j];
    }
}

// modBR[b,h,j] = baseBR[h,j] * (1 + gate(b,h, min(rev(j), 8192-rev(j))))
__global__ __launch_bounds__(256) void kern_mod(const float* __restrict__ baseBR,
                                                const float* __restrict__ ctrl,
                                                float* __restrict__ modBR) {
    const int bh = blockIdx.y;
    const int j = blockIdx.x * 256 + threadIdx.x;
    const int b = bh >> 4, h = bh & 15;
    int k = (int)(__brev((unsigned)j) >> 19);
    int kk = min(k, PAD_ - k);
    float ip = (float)kk * ((float)(NC_ - 1) / (float)(FB_ - 1));
    int il = min((int)ip, NC_ - 2);
    float iw = ip - (float)il;
    const float* cp = ctrl + b * (H_ * NC_) + h * NC_;
    float m = 1.f + cp[il] * (1.f - iw) + cp[il + 1] * iw;
    float br = baseBR[(size_t)(h * PAD_ + j) * 2 + 0];
    float bi = baseBR[(size_t)(h * PAD_ + j) * 2 + 1];
    modBR[(size_t)(bh * PAD_ + j) * 2 + 0] = br * m;
    modBR[(size_t)(bh * PAD_ + j) * 2 + 1] = bi * m;
}

// main FFT convolution, in place over field (one block per (b,h,c) signal)
__global__ __launch_bounds__(256) void kern_conv_fft(float* __restrict__ field,
                                                     const float* __restrict__ modBR) {
    __shared__ float xr[PAD_];
    __shared__ float xi[PAD_];
    const int sig = blockIdx.x, tid = threadIdx.x;
    const int bh = sig >> 7;
    float* row = field + (size_t)sig * F_;
    for (int f = tid; f < PAD_; f += 256) {
        xr[f] = (f < F_) ? row[f] : 0.f;
        xi[f] = 0.f;
    }
    __syncthreads();
    fft_fwd_dif(xr, xi, tid);
    const float* mp = modBR + (size_t)bh * PAD_ * 2;
    for (int j = tid; j < PAD_; j += 256) {
        float mr = mp[j * 2], mi = mp[j * 2 + 1];
        float ar = xr[j], ai = xi[j];
        xr[j] = ar * mr - ai * mi;
        xi[j] = ar * mi + ai * mr;
    }
    __syncthreads();
    fft_inv_dit(xr, xi, tid);
    const float scale = 1.f / (float)PAD_;
    for (int f = tid; f < F_; f += 256) row[f] = xr[f] * scale;
}

// head coupling IN PLACE: field[b,h,c,f] = sum_g coupling[h,g]*field_old[b,g,c,f]
// One block owns the disjoint set (b, all heads, c, f-chunk) -> safe in place.
__global__ __launch_bounds__(256) void kern_coupling(float* __restrict__ field,
                                                     const float* __restrict__ coupling) {
    __shared__ float cp[16][16];
    const int tid = threadIdx.x;
    cp[tid >> 4][tid & 15] = coupling[tid];
    __syncthreads();
    const int f = blockIdx.x * 256 + tid;
    const int c = blockIdx.y;
    const int b = blockIdx.z;
    float val[16];
#pragma unroll
    for (int g = 0; g < 16; ++g)
        val[g] = field[((size_t)(b * 16 + g) * 128 + c) * F_ + f];
    float out[16];
#pragma unroll
    for (int hh = 0; hh < 16; ++hh) {
        float s = 0.f;
#pragma unroll
        for (int g = 0; g < 16; ++g) s += cp[hh][g] * val[g];
        out[hh] = s;
    }
#pragma unroll
    for (int hh = 0; hh < 16; ++hh)
        field[((size_t)(b * 16 + hh) * 128 + c) * F_ + f] = out[hh];
}

// combine: out_h = phi_q * y_num / (|sum phi_q*y_den| + 1e-4) * sigmoid(g)
// 1024 threads = 16 waves = 16 consecutive tokens of one (b,h); lane = channel.
// phi_q lives in qkvg k-columns; att is written into qkvg q-columns.
__global__ __launch_bounds__(1024) void kern_combine(float* __restrict__ qkvg,
                                                     const float* __restrict__ field) {
    const int tid = threadIdx.x;
    const int lane = tid & 63, wv = tid >> 6;
    const int n = blockIdx.x * 16 + wv;
    const int h = blockIdx.y, b = blockIdx.z;
    const int f = min(n, F_ - 2);
    const size_t row = (size_t)(b * N_ + n) * 4096;
    float pq = qkvg[row + D_ + h * 64 + lane];
    const float* cv = field + (size_t)(b * H_ + h) * 128 * F_;
    float ynum = cv[(size_t)lane * F_ + f];
    float yden = cv[(size_t)(64 + lane) * F_ + f];
    float gv = qkvg[row + 3 * D_ + h * 64 + lane];
    float s = pq * yden;
    for (int m = 1; m < 64; m <<= 1) s += __shfl_xor(s, m);
    float den = fabsf(s) + 1e-4f;
    float o = pq * ynum / den * (1.f / (1.f + expf(-gv)));
    qkvg[row + h * 64 + lane] = o;
}

// ---------------------------------------------------------------------------
extern "C" void kernel_launch(void* const* d_in, const int* in_sizes, int n_in,
                              void* d_out, int out_size, void* d_ws, size_t ws_size,
                              hipStream_t stream) {
    const float* x      = (const float*)d_in[0];
    const float* w_qkvg = (const float*)d_in[1];
    const float* b_qkvg = (const float*)d_in[2];
    const float* w_out  = (const float*)d_in[3];
    const float* b_out  = (const float*)d_in[4];
    const float* qfm_w  = (const float*)d_in[5];
    const float* qfm_b  = (const float*)d_in[6];
    const float* kfm_w  = (const float*)d_in[7];
    const float* kfm_b  = (const float*)d_in[8];
    const float* wg_w   = (const float*)d_in[9];
    const float* wg_b   = (const float*)d_in[10];
    const float* ln_g   = (const float*)d_in[11];
    const float* ln_b   = (const float*)d_in[12];
    const float* sg_w1  = (const float*)d_in[13];
    const float* sg_b1  = (const float*)d_in[14];
    const float* sg_w2  = (const float*)d_in[15];
    const float* sg_b2  = (const float*)d_in[16];
    const float* wfreq  = (const float*)d_in[17];
    const float* wdamp  = (const float*)d_in[18];
    const float* wphase = (const float*)d_in[19];
    const float* coup   = (const float*)d_in[20];

    float* ws = (float*)d_ws;
    // workspace layout (floats). total 51,652,608 floats = 206.6 MB
    float* qkvg   = ws;                 // 33,554,432  (k-cols reused for phi_q, q-cols for att)
    float* field  = ws + 33554432;      // 16,777,216  (conv + coupling in place)
    float* baseBR = ws + 50331648;      //    262,144
    float* modBR  = ws + 50593792;      //  1,048,576
    float* q0n    = ws + 51642368;      //      4,096
    float* h1     = ws + 51646464;      //      4,096
    float* ctrl   = ws + 51650560;      //      2,048

    // 1. qkvg = x @ w_qkvg^T + b_qkvg            (8192 x 4096, K=1024)
    gemm_nt<<<dim3(4096 / 64, 8192 / 64), 256, 0, stream>>>(
        x, w_qkvg, b_qkvg, qkvg, B_ * N_, 4 * D_, D_, D_, 0);

    // 2. control path BEFORE feat (reads raw q token 0)
    kern_ln<<<B_ * H_, 64, 0, stream>>>(qkvg, ln_g, ln_b, q0n);
    gemm_nt<<<dim3(1024 / 64, 1), 256, 0, stream>>>(q0n, sg_w1, sg_b1, h1, B_, D_, D_, D_, 1);
    gemm_nt<<<dim3(512 / 64, 1), 256, 0, stream>>>(h1, sg_w2, sg_b2, ctrl, B_, H_ * NC_, D_, D_, 0);

    // 3. featmaps + wg + field build (phi_q -> qkvg k-columns)
    kern_feat<<<dim3(N_ / 64, H_, B_), 256, 0, stream>>>(
        qkvg, qfm_w, qfm_b, kfm_w, kfm_b, wg_w, wg_b, field);

    // 4. base spectrum + per-(b,h) modulated spectrum (bit-reversed layout)
    kern_base_fft<<<H_, 256, 0, stream>>>(wfreq, wdamp, wphase, baseBR);
    kern_mod<<<dim3(PAD_ / 256, B_ * H_), 256, 0, stream>>>(baseBR, ctrl, modBR);

    // 5. FFT convolution (in place on field)
    kern_conv_fft<<<B_ * H_ * 128, 256, 0, stream>>>(field, modBR);

    // 6. head coupling (in place on field)
    kern_coupling<<<dim3(F_ / 256, 128, B_), 256, 0, stream>>>(field, coup);

    // 7. combine -> att written into qkvg q-columns
    kern_combine<<<dim3(N_ / 16, H_, B_), 1024, 0, stream>>>(qkvg, field);

    // 8. out = att @ w_out^T + b_out   (att = qkvg q-columns, lda 4096)
    gemm_nt<<<dim3(1024 / 64, 8192 / 64), 256, 0, stream>>>(
        qkvg, w_out, b_out, (float*)d_out, B_ * N_, D_, D_, 4096, 0);
}

// Round 4
// 2009.576 us; speedup vs baseline: 1.3905x; 1.3905x over previous
//
#include <hip/hip_runtime.h>
#include <math.h>

// Problem constants
#define B_   4
#define N_   2048
#define D_   1024
#define H_   16
#define d_   64
#define F_   2048
#define PAD_ 8192
#define FB_  4097
#define NC_  32
#define EPS_ 1e-6f
#define PI_F 3.14159265358979323846f
#define PI_D 3.14159265358979323846

// ---------------------------------------------------------------------------
// Generic fp32 NT GEMM: C[m,n] = act( sum_k A[m,k]*B[n,k] + bias[n] )
// ---------------------------------------------------------------------------
__device__ __forceinline__ float gelu_f(float x) {
    return 0.5f * x * (1.f + tanhf(0.7978845608028654f * (x + 0.044715f * x * x * x)));
}

__global__ __launch_bounds__(256) void gemm_nt(const float* __restrict__ A,
                                               const float* __restrict__ Bm,
                                               const float* __restrict__ bias,
                                               float* __restrict__ C,
                                               int M, int Nn, int K, int lda, int act) {
    __shared__ float As[16][64];
    __shared__ float Bs[16][64];
    const int tid = threadIdx.x;
    const int tx = tid & 15, ty = tid >> 4;
    const int m0 = blockIdx.y * 64, n0 = blockIdx.x * 64;

    float acc[4][4];
#pragma unroll
    for (int i = 0; i < 4; ++i)
#pragma unroll
        for (int j = 0; j < 4; ++j) acc[i][j] = 0.f;

    const int lr = tid >> 2;
    const int lk = (tid & 3) * 4;

    for (int k0 = 0; k0 < K; k0 += 16) {
        float4 av = make_float4(0.f, 0.f, 0.f, 0.f);
        float4 bv = make_float4(0.f, 0.f, 0.f, 0.f);
        if (m0 + lr < M)
            av = *(const float4*)(A + (size_t)(m0 + lr) * lda + k0 + lk);
        if (n0 + lr < Nn)
            bv = *(const float4*)(Bm + (size_t)(n0 + lr) * K + k0 + lk);
        As[lk + 0][lr] = av.x; As[lk + 1][lr] = av.y;
        As[lk + 2][lr] = av.z; As[lk + 3][lr] = av.w;
        Bs[lk + 0][lr] = bv.x; Bs[lk + 1][lr] = bv.y;
        Bs[lk + 2][lr] = bv.z; Bs[lk + 3][lr] = bv.w;
        __syncthreads();
#pragma unroll
        for (int k = 0; k < 16; ++k) {
            float a[4], b[4];
#pragma unroll
            for (int i = 0; i < 4; ++i) a[i] = As[k][ty * 4 + i];
#pragma unroll
            for (int j = 0; j < 4; ++j) b[j] = Bs[k][tx * 4 + j];
#pragma unroll
            for (int i = 0; i < 4; ++i)
#pragma unroll
                for (int j = 0; j < 4; ++j) acc[i][j] += a[i] * b[j];
        }
        __syncthreads();
    }
#pragma unroll
    for (int i = 0; i < 4; ++i) {
        int row = m0 + ty * 4 + i;
        if (row >= M) continue;
#pragma unroll
        for (int j = 0; j < 4; ++j) {
            int col = n0 + tx * 4 + j;
            if (col >= Nn) continue;
            float v = acc[i][j] + bias[col];
            if (act == 1) v = gelu_f(v);
            C[(size_t)row * Nn + col] = v;
        }
    }
}

// ---------------------------------------------------------------------------
// Featuremap + field build (K path first, then Q path; phi_q -> qkvg k-cols).
// ---------------------------------------------------------------------------
__global__ __launch_bounds__(256) void kern_feat(float* __restrict__ qkvg,
                                                 const float* __restrict__ qfm_w,
                                                 const float* __restrict__ qfm_b,
                                                 const float* __restrict__ kfm_w,
                                                 const float* __restrict__ kfm_b,
                                                 const float* __restrict__ wg_w,
                                                 const float* __restrict__ wg_b,
                                                 float* __restrict__ field) {
    __shared__ float in_t[64][65];
    __shared__ float tmp[64][65];
    __shared__ float wbuf[64][65];
    __shared__ float bsm[64];
    __shared__ float wsm[64];
    __shared__ float wgbuf[64];

    const int tid = threadIdx.x;
    const int lane = tid & 63, grp = tid >> 6;
    const int n0 = blockIdx.x * 64;
    const int h = blockIdx.y, b = blockIdx.z;
    const size_t rowbase = (size_t)(b * N_ + n0) * 4096;

    // ============ K path ============
    for (int it = 0; it < 16; ++it) {
        int i = grp + 4 * it;
        in_t[i][lane] = qkvg[rowbase + (size_t)i * 4096 + D_ + h * 64 + lane];
    }
    for (int it = 0; it < 16; ++it) {
        int r = grp + 4 * it;
        wbuf[lane][r] = kfm_w[(size_t)r * 64 + lane];
    }
    if (tid < 64) { bsm[tid] = kfm_b[tid]; wsm[tid] = wg_w[tid]; }
    __syncthreads();
    if (tid < 64) {
        float s = 0.f;
        for (int c = 0; c < 64; ++c) s += in_t[tid][c] * wsm[c];
        s += wg_b[0];
        wgbuf[tid] = 1.f / (1.f + expf(-s));
    }
    {
        const int j = lane, ibase = grp * 16;
        float acc[16];
#pragma unroll
        for (int ii = 0; ii < 16; ++ii) acc[ii] = 0.f;
        for (int c = 0; c < 64; ++c) {
            float w = wbuf[c][j];
#pragma unroll
            for (int ii = 0; ii < 16; ++ii) acc[ii] += in_t[ibase + ii][c] * w;
        }
        float bj = bsm[j];
#pragma unroll
        for (int ii = 0; ii < 16; ++ii) tmp[ibase + ii][j] = fmaxf(acc[ii] + bj, 0.f);
    }
    __syncthreads();
    for (int it = 0; it < 16; ++it) {
        int r = grp + 4 * it;
        wbuf[lane][r] = kfm_w[(size_t)(64 + r) * 64 + lane];
    }
    if (tid < 64) bsm[tid] = kfm_b[64 + tid];
    __syncthreads();
    {
        const int j = lane, ibase = grp * 16;
        float acc[16];
#pragma unroll
        for (int ii = 0; ii < 16; ++ii) acc[ii] = 0.f;
        for (int c = 0; c < 64; ++c) {
            float w = wbuf[c][j];
#pragma unroll
            for (int ii = 0; ii < 16; ++ii) acc[ii] += tmp[ibase + ii][c] * w;
        }
        float bj = bsm[j];
#pragma unroll
        for (int ii = 0; ii < 16; ++ii)
            in_t[ibase + ii][j] = fmaxf(acc[ii] + bj, 0.f) + EPS_;
    }
    __syncthreads();
    for (int it = 0; it < 16; ++it) {
        int i = grp + 4 * it;
        tmp[i][lane] = qkvg[rowbase + (size_t)i * 4096 + 2 * D_ + h * 64 + lane];
    }
    __syncthreads();

    {
        float* frow = field + (size_t)(b * H_ + h) * 128 * F_;
        const bool last = (n0 == N_ - 64);
        for (int c = grp; c < 128; c += 4) {
            int i = lane;
            float v = (c < 64) ? wgbuf[i] * in_t[i][c] * tmp[i][c]
                               : wgbuf[i] * in_t[i][c - 64];
            if (last) {
                if (i == 62) {
                    float v2 = (c < 64) ? wgbuf[63] * in_t[63][c] * tmp[63][c]
                                        : wgbuf[63] * in_t[63][c - 64];
                    v += v2;
                } else if (i == 63) v = 0.f;
            }
            frow[(size_t)c * F_ + n0 + i] = v;
        }
    }
    __syncthreads();

    // ============ Q path ============
    for (int it = 0; it < 16; ++it) {
        int i = grp + 4 * it;
        in_t[i][lane] = qkvg[rowbase + (size_t)i * 4096 + h * 64 + lane];
    }
    for (int it = 0; it < 16; ++it) {
        int r = grp + 4 * it;
        wbuf[lane][r] = qfm_w[(size_t)r * 64 + lane];
    }
    if (tid < 64) bsm[tid] = qfm_b[tid];
    __syncthreads();
    {
        const int j = lane, ibase = grp * 16;
        float acc[16];
#pragma unroll
        for (int ii = 0; ii < 16; ++ii) acc[ii] = 0.f;
        for (int c = 0; c < 64; ++c) {
            float w = wbuf[c][j];
#pragma unroll
            for (int ii = 0; ii < 16; ++ii) acc[ii] += in_t[ibase + ii][c] * w;
        }
        float bj = bsm[j];
#pragma unroll
        for (int ii = 0; ii < 16; ++ii) tmp[ibase + ii][j] = fmaxf(acc[ii] + bj, 0.f);
    }
    __syncthreads();
    for (int it = 0; it < 16; ++it) {
        int r = grp + 4 * it;
        wbuf[lane][r] = qfm_w[(size_t)(64 + r) * 64 + lane];
    }
    if (tid < 64) bsm[tid] = qfm_b[64 + tid];
    __syncthreads();
    {
        const int j = lane, ibase = grp * 16;
        float acc[16];
#pragma unroll
        for (int ii = 0; ii < 16; ++ii) acc[ii] = 0.f;
        for (int c = 0; c < 64; ++c) {
            float w = wbuf[c][j];
#pragma unroll
            for (int ii = 0; ii < 16; ++ii) acc[ii] += tmp[ibase + ii][c] * w;
        }
        float bj = bsm[j];
#pragma unroll
        for (int ii = 0; ii < 16; ++ii) {
            float v = fmaxf(acc[ii] + bj, 0.f) + EPS_;
            qkvg[rowbase + (size_t)(ibase + ii) * 4096 + D_ + h * 64 + j] = v;
        }
    }
}

// ---------------------------------------------------------------------------
// LayerNorm of q token 0 -> q0n (B x 1024).
// ---------------------------------------------------------------------------
__global__ void kern_ln(const float* __restrict__ qkvg,
                        const float* __restrict__ ln_g,
                        const float* __restrict__ ln_b,
                        float* __restrict__ q0n) {
    const int bh = blockIdx.x, c = threadIdx.x;
    const int b = bh >> 4, h = bh & 15;
    float x = qkvg[(size_t)(b * N_) * 4096 + h * 64 + c];
    float mu = x;
    for (int m = 1; m < 64; m <<= 1) mu += __shfl_xor(mu, m);
    mu *= (1.f / 64.f);
    float dv = (x - mu) * (x - mu);
    for (int m = 1; m < 64; m <<= 1) dv += __shfl_xor(dv, m);
    float var = dv * (1.f / 64.f);
    q0n[b * 1024 + h * 64 + c] = (x - mu) * rsqrtf(var + 1e-5f) * ln_g[c] + ln_b[c];
}

// ---------------------------------------------------------------------------
// Twiddle table: twid[lh*4096 + t] = exp(-i*pi*(t&(hh-1))/hh), hh=1<<lh,
// lh in [0,13). Computed in double, stored fp32 (0.5 ulp).
// Serves the 8192-pt FFTs (t<4096) and the 4096/2048-pt ones (prefix rows).
// ---------------------------------------------------------------------------
__global__ __launch_bounds__(256) void kern_twid8(float2* __restrict__ twid) {
    const int idx = blockIdx.x * 256 + threadIdx.x;    // 13*4096 entries
    const int lh = idx >> 12, t = idx & 4095;
    const int hh = 1 << lh;
    const int j = t & (hh - 1);
    double s, c;
    sincos(-PI_D * (double)j / (double)hh, &s, &c);
    twid[idx] = make_float2((float)c, (float)s);
}

// ---------------------------------------------------------------------------
// Table-driven radix-2 FFT helpers on LDS.
// DIF fwd: natural->BR.  DIT inv: BR->natural (uses conj of table).
// ---------------------------------------------------------------------------
__device__ __forceinline__ void fft_fwd_dif_t(float* xr, float* xi, int tid, int logn,
                                              const float2* __restrict__ twid) {
    const int nb = 1 << (logn - 1);
    for (int lh = logn - 1; lh >= 0; --lh) {
        const int hh = 1 << lh;
        const float2* tws = twid + lh * 4096;
        for (int t = tid; t < nb; t += 256) {
            int j = t & (hh - 1);
            int i1 = ((t >> lh) << (lh + 1)) | j;
            int i2 = i1 + hh;
            float2 tw = tws[t];
            float ar = xr[i1], ai = xi[i1];
            float br = xr[i2], bi = xi[i2];
            xr[i1] = ar + br; xi[i1] = ai + bi;
            float tr = ar - br, ti = ai - bi;
            xr[i2] = tr * tw.x - ti * tw.y;
            xi[i2] = tr * tw.y + ti * tw.x;
        }
        __syncthreads();
    }
}

__device__ __forceinline__ void fft_inv_dit_t(float* xr, float* xi, int tid, int logn,
                                              const float2* __restrict__ twid) {
    const int nb = 1 << (logn - 1);
    for (int lh = 0; lh < logn; ++lh) {
        const int hh = 1 << lh;
        const float2* tws = twid + lh * 4096;
        for (int t = tid; t < nb; t += 256) {
            int j = t & (hh - 1);
            int i1 = ((t >> lh) << (lh + 1)) | j;
            int i2 = i1 + hh;
            float2 tw = tws[t];   // conj applied below
            float br = xr[i2], bi = xi[i2];
            float tr = br * tw.x + bi * tw.y;
            float ti = bi * tw.x - br * tw.y;
            float ar = xr[i1], ai = xi[i1];
            xr[i1] = ar + tr; xi[i1] = ai + ti;
            xr[i2] = ar - tr; xi[i2] = ai - ti;
        }
        __syncthreads();
    }
}

// base spectrum (BR order, 8192-pt) of the damped-cosine kernel, per head
__global__ __launch_bounds__(256) void kern_base_fft(const float* __restrict__ freq,
                                                     const float* __restrict__ damp,
                                                     const float* __restrict__ phase,
                                                     const float2* __restrict__ twid,
                                                     float* __restrict__ baseBR) {
    __shared__ float xr[PAD_];
    __shared__ float xi[PAD_];
    const int h = blockIdx.x, tid = threadIdx.x;
    const float fr = freq[h], ed = expf(damp[h]), ph = phase[h];
    for (int f = tid; f < PAD_; f += 256) {
        float v = 0.f;
        if (f < F_) {
            float t = (float)f / (float)F_;
            v = expf(-ed * t) * cosf(fr * t + ph);
        }
        xr[f] = v; xi[f] = 0.f;
    }
    __syncthreads();
    fft_fwd_dif_t(xr, xi, tid, 13, twid);
    for (int j = tid; j < PAD_; j += 256) {
        baseBR[(size_t)(h * PAD_ + j) * 2 + 0] = xr[j];
        baseBR[(size_t)(h * PAD_ + j) * 2 + 1] = xi[j];
    }
}

// Per (b,h): mod spectrum (8192, BR) -> keff -> fold to 4096 -> FFT -> GBR.
__global__ __launch_bounds__(256) void kern_prep(const float* __restrict__ baseBR,
                                                 const float* __restrict__ ctrl,
                                                 const float2* __restrict__ twid,
                                                 float* __restrict__ GBR) {
    __shared__ float xr[PAD_];
    __shared__ float xi[PAD_];
    const int bh = blockIdx.x, tid = threadIdx.x;
    const int b = bh >> 4, h = bh & 15;
    const float* cp = ctrl + b * (H_ * NC_) + h * NC_;
    for (int j = tid; j < PAD_; j += 256) {
        int k = (int)(__brev((unsigned)j) >> 19);      // bitrev13 -> natural bin
        int kk = min(k, PAD_ - k);
        float ip = (float)kk * ((float)(NC_ - 1) / (float)(FB_ - 1));
        int il = min((int)ip, NC_ - 2);
        float iw = ip - (float)il;
        float m = 1.f + cp[il] * (1.f - iw) + cp[il + 1] * iw;
        xr[j] = baseBR[(size_t)(h * PAD_ + j) * 2 + 0] * m;
        xi[j] = baseBR[(size_t)(h * PAD_ + j) * 2 + 1] * m;
    }
    __syncthreads();
    fft_inv_dit_t(xr, xi, tid, 13, twid);  // BR -> natural keff (unscaled)
    const float s = 1.f / (float)PAD_;
    for (int j = tid; j < 4096; j += 256) {
        float v = (j < 2048) ? xr[j] : xr[j + 4096];
        xr[j] = v * s;
        xi[j] = 0.f;
    }
    __syncthreads();
    fft_fwd_dif_t(xr, xi, tid, 12, twid);  // natural -> BR (4096)
    for (int j = tid; j < 4096; j += 256) {
        GBR[((size_t)bh * 4096 + j) * 2 + 0] = xr[j];
        GBR[((size_t)bh * 4096 + j) * 2 + 1] = xi[j];
    }
}

// Main conv: 4096-pt complex FFT, 2 real channels packed per block.
__global__ __launch_bounds__(256) void kern_conv4(float* __restrict__ field,
                                                  const float* __restrict__ GBR,
                                                  const float2* __restrict__ twid) {
    __shared__ float2 z[4096];
    const int tid = threadIdx.x;
    const int bh = blockIdx.x >> 6, cp = blockIdx.x & 63;
    float* rowx = field + ((size_t)bh * 128 + 2 * cp) * F_;
    float* rowy = rowx + F_;

    for (int f = tid; f < 2048; f += 256) {
        z[f] = make_float2(rowx[f], rowy[f]);
        z[f + 2048] = make_float2(0.f, 0.f);
    }
    __syncthreads();

    // forward DIF (natural -> BR)
    for (int lh = 11; lh >= 0; --lh) {
        const int hh = 1 << lh;
        const float2* tws = twid + lh * 4096;
        for (int t = tid; t < 2048; t += 256) {
            int j = t & (hh - 1);
            int i1 = ((t >> lh) << (lh + 1)) | j;
            int i2 = i1 + hh;
            float2 tw = tws[t];
            float2 a = z[i1], bv = z[i2];
            z[i1] = make_float2(a.x + bv.x, a.y + bv.y);
            float dr = a.x - bv.x, di = a.y - bv.y;
            z[i2] = make_float2(dr * tw.x - di * tw.y, dr * tw.y + di * tw.x);
        }
        __syncthreads();
    }

    // pointwise multiply by G (BR order)
    {
        const float2* G = (const float2*)(GBR) + (size_t)bh * 4096;
        for (int j = tid; j < 4096; j += 256) {
            float2 g = G[j];
            float2 a = z[j];
            z[j] = make_float2(a.x * g.x - a.y * g.y, a.x * g.y + a.y * g.x);
        }
    }
    __syncthreads();

    // inverse DIT (BR -> natural), conj twiddles
    for (int lh = 0; lh <= 11; ++lh) {
        const int hh = 1 << lh;
        const float2* tws = twid + lh * 4096;
        for (int t = tid; t < 2048; t += 256) {
            int j = t & (hh - 1);
            int i1 = ((t >> lh) << (lh + 1)) | j;
            int i2 = i1 + hh;
            float2 tw = tws[t];
            float2 bv = z[i2];
            float tr = bv.x * tw.x + bv.y * tw.y;
            float ti = bv.y * tw.x - bv.x * tw.y;
            float2 a = z[i1];
            z[i1] = make_float2(a.x + tr, a.y + ti);
            z[i2] = make_float2(a.x - tr, a.y - ti);
        }
        __syncthreads();
    }

    const float s = 1.f / 4096.f;
    for (int f = tid; f < 2048; f += 256) {
        float2 v = z[f];
        rowx[f] = v.x * s;
        rowy[f] = v.y * s;
    }
}

// head coupling IN PLACE
__global__ __launch_bounds__(256) void kern_coupling(float* __restrict__ field,
                                                     const float* __restrict__ coupling) {
    __shared__ float cp[16][16];
    const int tid = threadIdx.x;
    cp[tid >> 4][tid & 15] = coupling[tid];
    __syncthreads();
    const int f = blockIdx.x * 256 + tid;
    const int c = blockIdx.y;
    const int b = blockIdx.z;
    float val[16];
#pragma unroll
    for (int g = 0; g < 16; ++g)
        val[g] = field[((size_t)(b * 16 + g) * 128 + c) * F_ + f];
    float out[16];
#pragma unroll
    for (int hh = 0; hh < 16; ++hh) {
        float s = 0.f;
#pragma unroll
        for (int g = 0; g < 16; ++g) s += cp[hh][g] * val[g];
        out[hh] = s;
    }
#pragma unroll
    for (int hh = 0; hh < 16; ++hh)
        field[((size_t)(b * 16 + hh) * 128 + c) * F_ + f] = out[hh];
}

// combine -> att written into qkvg q-columns
__global__ __launch_bounds__(1024) void kern_combine(float* __restrict__ qkvg,
                                                     const float* __restrict__ field) {
    const int tid = threadIdx.x;
    const int lane = tid & 63, wv = tid >> 6;
    const int n = blockIdx.x * 16 + wv;
    const int h = blockIdx.y, b = blockIdx.z;
    const int f = min(n, F_ - 2);
    const size_t row = (size_t)(b * N_ + n) * 4096;
    float pq = qkvg[row + D_ + h * 64 + lane];
    const float* cv = field + (size_t)(b * H_ + h) * 128 * F_;
    float ynum = cv[(size_t)lane * F_ + f];
    float yden = cv[(size_t)(64 + lane) * F_ + f];
    float gv = qkvg[row + 3 * D_ + h * 64 + lane];
    float s = pq * yden;
    for (int m = 1; m < 64; m <<= 1) s += __shfl_xor(s, m);
    float den = fabsf(s) + 1e-4f;
    float o = pq * ynum / den * (1.f / (1.f + expf(-gv)));
    qkvg[row + h * 64 + lane] = o;
}

// ---------------------------------------------------------------------------
extern "C" void kernel_launch(void* const* d_in, const int* in_sizes, int n_in,
                              void* d_out, int out_size, void* d_ws, size_t ws_size,
                              hipStream_t stream) {
    const float* x      = (const float*)d_in[0];
    const float* w_qkvg = (const float*)d_in[1];
    const float* b_qkvg = (const float*)d_in[2];
    const float* w_out  = (const float*)d_in[3];
    const float* b_out  = (const float*)d_in[4];
    const float* qfm_w  = (const float*)d_in[5];
    const float* qfm_b  = (const float*)d_in[6];
    const float* kfm_w  = (const float*)d_in[7];
    const float* kfm_b  = (const float*)d_in[8];
    const float* wg_w   = (const float*)d_in[9];
    const float* wg_b   = (const float*)d_in[10];
    const float* ln_g   = (const float*)d_in[11];
    const float* ln_b   = (const float*)d_in[12];
    const float* sg_w1  = (const float*)d_in[13];
    const float* sg_b1  = (const float*)d_in[14];
    const float* sg_w2  = (const float*)d_in[15];
    const float* sg_b2  = (const float*)d_in[16];
    const float* wfreq  = (const float*)d_in[17];
    const float* wdamp  = (const float*)d_in[18];
    const float* wphase = (const float*)d_in[19];
    const float* coup   = (const float*)d_in[20];

    float* ws = (float*)d_ws;
    // workspace layout (floats). total ~51.24M floats = 205 MB
    float*  qkvg   = ws;                 // 33,554,432  (k-cols -> phi_q, q-cols -> att)
    float*  field  = ws + 33554432;      // 16,777,216  (conv + coupling in place)
    float*  baseBR = ws + 50331648;      //    262,144
    float*  GBR    = ws + 50593792;      //    524,288
    float2* twid   = (float2*)(ws + 51118080);  // 13*4096 float2 = 106,496 floats
    float*  q0n    = ws + 51224576;      //      4,096
    float*  h1     = ws + 51228672;      //      4,096
    float*  ctrl   = ws + 51232768;      //      2,048

    // 0. twiddle table (double-precision sincos -> fp32)
    kern_twid8<<<(13 * 4096) / 256, 256, 0, stream>>>(twid);

    // 1. qkvg = x @ w_qkvg^T + b_qkvg
    gemm_nt<<<dim3(4096 / 64, 8192 / 64), 256, 0, stream>>>(
        x, w_qkvg, b_qkvg, qkvg, B_ * N_, 4 * D_, D_, D_, 0);

    // 2. control path (reads raw q token 0 before feat overwrites)
    kern_ln<<<B_ * H_, 64, 0, stream>>>(qkvg, ln_g, ln_b, q0n);
    gemm_nt<<<dim3(1024 / 64, 1), 256, 0, stream>>>(q0n, sg_w1, sg_b1, h1, B_, D_, D_, D_, 1);
    gemm_nt<<<dim3(512 / 64, 1), 256, 0, stream>>>(h1, sg_w2, sg_b2, ctrl, B_, H_ * NC_, D_, D_, 0);

    // 3. featmaps + wg + field build
    kern_feat<<<dim3(N_ / 64, H_, B_), 256, 0, stream>>>(
        qkvg, qfm_w, qfm_b, kfm_w, kfm_b, wg_w, wg_b, field);

    // 4. spectra prep: base FFT (per h), folded G spectrum (per b,h)
    kern_base_fft<<<H_, 256, 0, stream>>>(wfreq, wdamp, wphase, twid, baseBR);
    kern_prep<<<B_ * H_, 256, 0, stream>>>(baseBR, ctrl, twid, GBR);

    // 5. FFT convolution: 4096-pt, 2 channels/block (in place on field)
    kern_conv4<<<B_ * H_ * 64, 256, 0, stream>>>(field, GBR, twid);

    // 6. head coupling (in place)
    kern_coupling<<<dim3(F_ / 256, 128, B_), 256, 0, stream>>>(field, coup);

    // 7. combine -> qkvg q-columns
    kern_combine<<<dim3(N_ / 16, H_, B_), 1024, 0, stream>>>(qkvg, field);

    // 8. out = att @ w_out^T + b_out
    gemm_nt<<<dim3(1024 / 64, 8192 / 64), 256, 0, stream>>>(
        qkvg, w_out, b_out, (float*)d_out, B_ * N_, D_, D_, 4096, 0);
}

// Round 5
// 1124.599 us; speedup vs baseline: 2.4847x; 1.7869x over previous
//
#include <hip/hip_runtime.h>
#include <math.h>

// Problem constants
#define B_   4
#define N_   2048
#define D_   1024
#define H_   16
#define d_   64
#define F_   2048
#define PAD_ 8192
#define FB_  4097
#define NC_  32
#define EPS_ 1e-6f
#define PI_F 3.14159265358979323846f
#define PI_D 3.14159265358979323846

typedef unsigned short ushort_t;
typedef short bf16x8 __attribute__((ext_vector_type(8)));
typedef float f32x4  __attribute__((ext_vector_type(4)));

#define GLD16(gp, lp) __builtin_amdgcn_global_load_lds( \
    (const __attribute__((address_space(1))) unsigned int*)(const void*)(gp), \
    (__attribute__((address_space(3))) unsigned int*)(void*)(lp), 16, 0, 0)

// round-to-nearest-even fp32 -> bf16 (bits), plus residual split
__device__ __forceinline__ ushort_t bf16_rne(float v) {
    unsigned b = __float_as_uint(v);
    unsigned rb = b + 0x7fffu + ((b >> 16) & 1u);
    return (ushort_t)(rb >> 16);
}
__device__ __forceinline__ void split_bf16(float v, ushort_t& h, ushort_t& l) {
    h = bf16_rne(v);
    float fh = __uint_as_float((unsigned)h << 16);
    l = bf16_rne(v - fh);
}

// ---------------------------------------------------------------------------
// kern_split: fp32 array -> (hi, lo) bf16 arrays
// ---------------------------------------------------------------------------
__global__ __launch_bounds__(256) void kern_split(const float* __restrict__ src,
                                                  ushort_t* __restrict__ hi,
                                                  ushort_t* __restrict__ lo, int n) {
    int i = blockIdx.x * 256 + threadIdx.x;
    if (i >= n) return;
    ushort_t h, l;
    split_bf16(src[i], h, l);
    hi[i] = h; lo[i] = l;
}

// ---------------------------------------------------------------------------
// Split-bf16 MFMA NT GEMM: C[m,n] = sum_k A[m,k]*B[n,k] + bias[n]
// A = Ah+Al, B = Bh+Bl (bf16 hi/lo). 128x128 tile, BK=32, 256 thr (4 waves),
// each wave 64x64 via 4x4 grid of 16x16x32 MFMAs, 4 cross-products -> fp32-
// accurate. Staging via global_load_lds width=16 (m97 structure).
// M, Nn, K all multiples of 128 (no bounds checks).
// ---------------------------------------------------------------------------
__global__ __launch_bounds__(256) void gemm_mfma(
        const ushort_t* __restrict__ Ah, const ushort_t* __restrict__ Al, int lda,
        const ushort_t* __restrict__ Bh, const ushort_t* __restrict__ Bl, int ldb,
        const float* __restrict__ bias, float* __restrict__ C,
        int Nn, int K) {
    __shared__ __align__(16) ushort_t At0[128 * 32];
    __shared__ __align__(16) ushort_t At1[128 * 32];
    __shared__ __align__(16) ushort_t Bt0[128 * 32];
    __shared__ __align__(16) ushort_t Bt1[128 * 32];

    const int tid = threadIdx.x;
    const int wv = tid >> 6, lane = tid & 63;
    const int quad = lane >> 4, lrow = lane & 15;
    const int m0 = blockIdx.y * 128, n0 = blockIdx.x * 128;
    const int mw = (wv >> 1) * 64, nw = (wv & 1) * 64;

    const int srow = lane >> 2;          // 0..15: tile row within 16-row group
    const int schunk = (lane & 3) * 8;   // 0,8,16,24: k-elem chunk

    f32x4 acc[4][4] = {};

    for (int k0 = 0; k0 < K; k0 += 32) {
        // ---- stage 4 tiles (hi/lo A/B), wave wv covers tile rows [wv*32, wv*32+32)
        {
            const size_t ga = (size_t)(m0 + wv * 32 + srow) * lda + k0 + schunk;
            const size_t gb = (size_t)(n0 + wv * 32 + srow) * ldb + k0 + schunk;
            const size_t ga2 = ga + (size_t)16 * lda;
            const size_t gb2 = gb + (size_t)16 * ldb;
            GLD16(Ah + ga,  &At0[(wv * 32) * 32]);
            GLD16(Ah + ga2, &At0[(wv * 32 + 16) * 32]);
            GLD16(Al + ga,  &At1[(wv * 32) * 32]);
            GLD16(Al + ga2, &At1[(wv * 32 + 16) * 32]);
            GLD16(Bh + gb,  &Bt0[(wv * 32) * 32]);
            GLD16(Bh + gb2, &Bt0[(wv * 32 + 16) * 32]);
            GLD16(Bl + gb,  &Bt1[(wv * 32) * 32]);
            GLD16(Bl + gb2, &Bt1[(wv * 32 + 16) * 32]);
        }
        __syncthreads();

        // ---- fragments (A: m=lane&15, k=quad*8+j ; B: n=lane&15, k=quad*8+j)
        bf16x8 a0[4], a1[4], b0[4], b1[4];
#pragma unroll
        for (int i = 0; i < 4; ++i) {
            a0[i] = *(const bf16x8*)&At0[(mw + i * 16 + lrow) * 32 + quad * 8];
            a1[i] = *(const bf16x8*)&At1[(mw + i * 16 + lrow) * 32 + quad * 8];
            b0[i] = *(const bf16x8*)&Bt0[(nw + i * 16 + lrow) * 32 + quad * 8];
            b1[i] = *(const bf16x8*)&Bt1[(nw + i * 16 + lrow) * 32 + quad * 8];
        }
#pragma unroll
        for (int mi = 0; mi < 4; ++mi)
#pragma unroll
            for (int nj = 0; nj < 4; ++nj) {
                acc[mi][nj] = __builtin_amdgcn_mfma_f32_16x16x32_bf16(a0[mi], b0[nj], acc[mi][nj], 0, 0, 0);
                acc[mi][nj] = __builtin_amdgcn_mfma_f32_16x16x32_bf16(a0[mi], b1[nj], acc[mi][nj], 0, 0, 0);
                acc[mi][nj] = __builtin_amdgcn_mfma_f32_16x16x32_bf16(a1[mi], b0[nj], acc[mi][nj], 0, 0, 0);
                acc[mi][nj] = __builtin_amdgcn_mfma_f32_16x16x32_bf16(a1[mi], b1[nj], acc[mi][nj], 0, 0, 0);
            }
        __syncthreads();
    }

    // ---- epilogue: D row = quad*4+r, col = lane&15
#pragma unroll
    for (int mi = 0; mi < 4; ++mi) {
        const int row = m0 + mw + mi * 16 + quad * 4;
#pragma unroll
        for (int nj = 0; nj < 4; ++nj) {
            const int col = n0 + nw + nj * 16 + lrow;
            const float bv = bias[col];
#pragma unroll
            for (int r = 0; r < 4; ++r)
                C[(size_t)(row + r) * Nn + col] = acc[mi][nj][r] + bv;
        }
    }
}

// ---------------------------------------------------------------------------
// Generic fp32 NT GEMM (only for the tiny M=4 control GEMMs now).
// ---------------------------------------------------------------------------
__device__ __forceinline__ float gelu_f(float x) {
    return 0.5f * x * (1.f + tanhf(0.7978845608028654f * (x + 0.044715f * x * x * x)));
}

__global__ __launch_bounds__(256) void gemm_nt(const float* __restrict__ A,
                                               const float* __restrict__ Bm,
                                               const float* __restrict__ bias,
                                               float* __restrict__ C,
                                               int M, int Nn, int K, int lda, int act) {
    __shared__ float As[16][64];
    __shared__ float Bs[16][64];
    const int tid = threadIdx.x;
    const int tx = tid & 15, ty = tid >> 4;
    const int m0 = blockIdx.y * 64, n0 = blockIdx.x * 64;

    float acc[4][4];
#pragma unroll
    for (int i = 0; i < 4; ++i)
#pragma unroll
        for (int j = 0; j < 4; ++j) acc[i][j] = 0.f;

    const int lr = tid >> 2;
    const int lk = (tid & 3) * 4;

    for (int k0 = 0; k0 < K; k0 += 16) {
        float4 av = make_float4(0.f, 0.f, 0.f, 0.f);
        float4 bv = make_float4(0.f, 0.f, 0.f, 0.f);
        if (m0 + lr < M)
            av = *(const float4*)(A + (size_t)(m0 + lr) * lda + k0 + lk);
        if (n0 + lr < Nn)
            bv = *(const float4*)(Bm + (size_t)(n0 + lr) * K + k0 + lk);
        As[lk + 0][lr] = av.x; As[lk + 1][lr] = av.y;
        As[lk + 2][lr] = av.z; As[lk + 3][lr] = av.w;
        Bs[lk + 0][lr] = bv.x; Bs[lk + 1][lr] = bv.y;
        Bs[lk + 2][lr] = bv.z; Bs[lk + 3][lr] = bv.w;
        __syncthreads();
#pragma unroll
        for (int k = 0; k < 16; ++k) {
            float a[4], b[4];
#pragma unroll
            for (int i = 0; i < 4; ++i) a[i] = As[k][ty * 4 + i];
#pragma unroll
            for (int j = 0; j < 4; ++j) b[j] = Bs[k][tx * 4 + j];
#pragma unroll
            for (int i = 0; i < 4; ++i)
#pragma unroll
                for (int j = 0; j < 4; ++j) acc[i][j] += a[i] * b[j];
        }
        __syncthreads();
    }
#pragma unroll
    for (int i = 0; i < 4; ++i) {
        int row = m0 + ty * 4 + i;
        if (row >= M) continue;
#pragma unroll
        for (int j = 0; j < 4; ++j) {
            int col = n0 + tx * 4 + j;
            if (col >= Nn) continue;
            float v = acc[i][j] + bias[col];
            if (act == 1) v = gelu_f(v);
            C[(size_t)row * Nn + col] = v;
        }
    }
}

// ---------------------------------------------------------------------------
// Featuremap + field build (K path first, then Q path; phi_q -> qkvg k-cols).
// ---------------------------------------------------------------------------
__global__ __launch_bounds__(256) void kern_feat(float* __restrict__ qkvg,
                                                 const float* __restrict__ qfm_w,
                                                 const float* __restrict__ qfm_b,
                                                 const float* __restrict__ kfm_w,
                                                 const float* __restrict__ kfm_b,
                                                 const float* __restrict__ wg_w,
                                                 const float* __restrict__ wg_b,
                                                 float* __restrict__ field) {
    __shared__ float in_t[64][65];
    __shared__ float tmp[64][65];
    __shared__ float wbuf[64][65];
    __shared__ float bsm[64];
    __shared__ float wsm[64];
    __shared__ float wgbuf[64];

    const int tid = threadIdx.x;
    const int lane = tid & 63, grp = tid >> 6;
    const int n0 = blockIdx.x * 64;
    const int h = blockIdx.y, b = blockIdx.z;
    const size_t rowbase = (size_t)(b * N_ + n0) * 4096;

    // ============ K path ============
    for (int it = 0; it < 16; ++it) {
        int i = grp + 4 * it;
        in_t[i][lane] = qkvg[rowbase + (size_t)i * 4096 + D_ + h * 64 + lane];
    }
    for (int it = 0; it < 16; ++it) {
        int r = grp + 4 * it;
        wbuf[lane][r] = kfm_w[(size_t)r * 64 + lane];
    }
    if (tid < 64) { bsm[tid] = kfm_b[tid]; wsm[tid] = wg_w[tid]; }
    __syncthreads();
    if (tid < 64) {
        float s = 0.f;
        for (int c = 0; c < 64; ++c) s += in_t[tid][c] * wsm[c];
        s += wg_b[0];
        wgbuf[tid] = 1.f / (1.f + expf(-s));
    }
    {
        const int j = lane, ibase = grp * 16;
        float acc[16];
#pragma unroll
        for (int ii = 0; ii < 16; ++ii) acc[ii] = 0.f;
        for (int c = 0; c < 64; ++c) {
            float w = wbuf[c][j];
#pragma unroll
            for (int ii = 0; ii < 16; ++ii) acc[ii] += in_t[ibase + ii][c] * w;
        }
        float bj = bsm[j];
#pragma unroll
        for (int ii = 0; ii < 16; ++ii) tmp[ibase + ii][j] = fmaxf(acc[ii] + bj, 0.f);
    }
    __syncthreads();
    for (int it = 0; it < 16; ++it) {
        int r = grp + 4 * it;
        wbuf[lane][r] = kfm_w[(size_t)(64 + r) * 64 + lane];
    }
    if (tid < 64) bsm[tid] = kfm_b[64 + tid];
    __syncthreads();
    {
        const int j = lane, ibase = grp * 16;
        float acc[16];
#pragma unroll
        for (int ii = 0; ii < 16; ++ii) acc[ii] = 0.f;
        for (int c = 0; c < 64; ++c) {
            float w = wbuf[c][j];
#pragma unroll
            for (int ii = 0; ii < 16; ++ii) acc[ii] += tmp[ibase + ii][c] * w;
        }
        float bj = bsm[j];
#pragma unroll
        for (int ii = 0; ii < 16; ++ii)
            in_t[ibase + ii][j] = fmaxf(acc[ii] + bj, 0.f) + EPS_;
    }
    __syncthreads();
    for (int it = 0; it < 16; ++it) {
        int i = grp + 4 * it;
        tmp[i][lane] = qkvg[rowbase + (size_t)i * 4096 + 2 * D_ + h * 64 + lane];
    }
    __syncthreads();

    {
        float* frow = field + (size_t)(b * H_ + h) * 128 * F_;
        const bool last = (n0 == N_ - 64);
        for (int c = grp; c < 128; c += 4) {
            int i = lane;
            float v = (c < 64) ? wgbuf[i] * in_t[i][c] * tmp[i][c]
                               : wgbuf[i] * in_t[i][c - 64];
            if (last) {
                if (i == 62) {
                    float v2 = (c < 64) ? wgbuf[63] * in_t[63][c] * tmp[63][c]
                                        : wgbuf[63] * in_t[63][c - 64];
                    v += v2;
                } else if (i == 63) v = 0.f;
            }
            frow[(size_t)c * F_ + n0 + i] = v;
        }
    }
    __syncthreads();

    // ============ Q path ============
    for (int it = 0; it < 16; ++it) {
        int i = grp + 4 * it;
        in_t[i][lane] = qkvg[rowbase + (size_t)i * 4096 + h * 64 + lane];
    }
    for (int it = 0; it < 16; ++it) {
        int r = grp + 4 * it;
        wbuf[lane][r] = qfm_w[(size_t)r * 64 + lane];
    }
    if (tid < 64) bsm[tid] = qfm_b[tid];
    __syncthreads();
    {
        const int j = lane, ibase = grp * 16;
        float acc[16];
#pragma unroll
        for (int ii = 0; ii < 16; ++ii) acc[ii] = 0.f;
        for (int c = 0; c < 64; ++c) {
            float w = wbuf[c][j];
#pragma unroll
            for (int ii = 0; ii < 16; ++ii) acc[ii] += in_t[ibase + ii][c] * w;
        }
        float bj = bsm[j];
#pragma unroll
        for (int ii = 0; ii < 16; ++ii) tmp[ibase + ii][j] = fmaxf(acc[ii] + bj, 0.f);
    }
    __syncthreads();
    for (int it = 0; it < 16; ++it) {
        int r = grp + 4 * it;
        wbuf[lane][r] = qfm_w[(size_t)(64 + r) * 64 + lane];
    }
    if (tid < 64) bsm[tid] = qfm_b[64 + tid];
    __syncthreads();
    {
        const int j = lane, ibase = grp * 16;
        float acc[16];
#pragma unroll
        for (int ii = 0; ii < 16; ++ii) acc[ii] = 0.f;
        for (int c = 0; c < 64; ++c) {
            float w = wbuf[c][j];
#pragma unroll
            for (int ii = 0; ii < 16; ++ii) acc[ii] += tmp[ibase + ii][c] * w;
        }
        float bj = bsm[j];
#pragma unroll
        for (int ii = 0; ii < 16; ++ii) {
            float v = fmaxf(acc[ii] + bj, 0.f) + EPS_;
            qkvg[rowbase + (size_t)(ibase + ii) * 4096 + D_ + h * 64 + j] = v;
        }
    }
}

// ---------------------------------------------------------------------------
// LayerNorm of q token 0 -> q0n (B x 1024).
// ---------------------------------------------------------------------------
__global__ void kern_ln(const float* __restrict__ qkvg,
                        const float* __restrict__ ln_g,
                        const float* __restrict__ ln_b,
                        float* __restrict__ q0n) {
    const int bh = blockIdx.x, c = threadIdx.x;
    const int b = bh >> 4, h = bh & 15;
    float x = qkvg[(size_t)(b * N_) * 4096 + h * 64 + c];
    float mu = x;
    for (int m = 1; m < 64; m <<= 1) mu += __shfl_xor(mu, m);
    mu *= (1.f / 64.f);
    float dv = (x - mu) * (x - mu);
    for (int m = 1; m < 64; m <<= 1) dv += __shfl_xor(dv, m);
    float var = dv * (1.f / 64.f);
    q0n[b * 1024 + h * 64 + c] = (x - mu) * rsqrtf(var + 1e-5f) * ln_g[c] + ln_b[c];
}

// ---------------------------------------------------------------------------
// Twiddle table: twid[lh*4096 + t] = exp(-i*pi*(t&(hh-1))/hh), hh=1<<lh,
// lh in [0,13). Double-precision sincos -> fp32.
// ---------------------------------------------------------------------------
__global__ __launch_bounds__(256) void kern_twid8(float2* __restrict__ twid) {
    const int idx = blockIdx.x * 256 + threadIdx.x;
    const int lh = idx >> 12, t = idx & 4095;
    const int hh = 1 << lh;
    const int j = t & (hh - 1);
    double s, c;
    sincos(-PI_D * (double)j / (double)hh, &s, &c);
    twid[idx] = make_float2((float)c, (float)s);
}

// ---------------------------------------------------------------------------
// Table-driven radix-2 FFT helpers on LDS.
// ---------------------------------------------------------------------------
__device__ __forceinline__ void fft_fwd_dif_t(float* xr, float* xi, int tid, int logn,
                                              const float2* __restrict__ twid) {
    const int nb = 1 << (logn - 1);
    for (int lh = logn - 1; lh >= 0; --lh) {
        const int hh = 1 << lh;
        const float2* tws = twid + lh * 4096;
        for (int t = tid; t < nb; t += 256) {
            int j = t & (hh - 1);
            int i1 = ((t >> lh) << (lh + 1)) | j;
            int i2 = i1 + hh;
            float2 tw = tws[t];
            float ar = xr[i1], ai = xi[i1];
            float br = xr[i2], bi = xi[i2];
            xr[i1] = ar + br; xi[i1] = ai + bi;
            float tr = ar - br, ti = ai - bi;
            xr[i2] = tr * tw.x - ti * tw.y;
            xi[i2] = tr * tw.y + ti * tw.x;
        }
        __syncthreads();
    }
}

__device__ __forceinline__ void fft_inv_dit_t(float* xr, float* xi, int tid, int logn,
                                              const float2* __restrict__ twid) {
    const int nb = 1 << (logn - 1);
    for (int lh = 0; lh < logn; ++lh) {
        const int hh = 1 << lh;
        const float2* tws = twid + lh * 4096;
        for (int t = tid; t < nb; t += 256) {
            int j = t & (hh - 1);
            int i1 = ((t >> lh) << (lh + 1)) | j;
            int i2 = i1 + hh;
            float2 tw = tws[t];   // conj applied
            float br = xr[i2], bi = xi[i2];
            float tr = br * tw.x + bi * tw.y;
            float ti = bi * tw.x - br * tw.y;
            float ar = xr[i1], ai = xi[i1];
            xr[i1] = ar + tr; xi[i1] = ai + ti;
            xr[i2] = ar - tr; xi[i2] = ai - ti;
        }
        __syncthreads();
    }
}

// base spectrum (BR order, 8192-pt) of the damped-cosine kernel, per head
__global__ __launch_bounds__(256) void kern_base_fft(const float* __restrict__ freq,
                                                     const float* __restrict__ damp,
                                                     const float* __restrict__ phase,
                                                     const float2* __restrict__ twid,
                                                     float* __restrict__ baseBR) {
    __shared__ float xr[PAD_];
    __shared__ float xi[PAD_];
    const int h = blockIdx.x, tid = threadIdx.x;
    const float fr = freq[h], ed = expf(damp[h]), ph = phase[h];
    for (int f = tid; f < PAD_; f += 256) {
        float v = 0.f;
        if (f < F_) {
            float t = (float)f / (float)F_;
            v = expf(-ed * t) * cosf(fr * t + ph);
        }
        xr[f] = v; xi[f] = 0.f;
    }
    __syncthreads();
    fft_fwd_dif_t(xr, xi, tid, 13, twid);
    for (int j = tid; j < PAD_; j += 256) {
        baseBR[(size_t)(h * PAD_ + j) * 2 + 0] = xr[j];
        baseBR[(size_t)(h * PAD_ + j) * 2 + 1] = xi[j];
    }
}

// Per (b,h): mod spectrum (8192, BR) -> keff -> fold to 4096 -> FFT -> GBR.
__global__ __launch_bounds__(256) void kern_prep(const float* __restrict__ baseBR,
                                                 const float* __restrict__ ctrl,
                                                 const float2* __restrict__ twid,
                                                 float* __restrict__ GBR) {
    __shared__ float xr[PAD_];
    __shared__ float xi[PAD_];
    const int bh = blockIdx.x, tid = threadIdx.x;
    const int b = bh >> 4, h = bh & 15;
    const float* cp = ctrl + b * (H_ * NC_) + h * NC_;
    for (int j = tid; j < PAD_; j += 256) {
        int k = (int)(__brev((unsigned)j) >> 19);
        int kk = min(k, PAD_ - k);
        float ip = (float)kk * ((float)(NC_ - 1) / (float)(FB_ - 1));
        int il = min((int)ip, NC_ - 2);
        float iw = ip - (float)il;
        float m = 1.f + cp[il] * (1.f - iw) + cp[il + 1] * iw;
        xr[j] = baseBR[(size_t)(h * PAD_ + j) * 2 + 0] * m;
        xi[j] = baseBR[(size_t)(h * PAD_ + j) * 2 + 1] * m;
    }
    __syncthreads();
    fft_inv_dit_t(xr, xi, tid, 13, twid);
    const float s = 1.f / (float)PAD_;
    for (int j = tid; j < 4096; j += 256) {
        float v = (j < 2048) ? xr[j] : xr[j + 4096];
        xr[j] = v * s;
        xi[j] = 0.f;
    }
    __syncthreads();
    fft_fwd_dif_t(xr, xi, tid, 12, twid);
    for (int j = tid; j < 4096; j += 256) {
        GBR[((size_t)bh * 4096 + j) * 2 + 0] = xr[j];
        GBR[((size_t)bh * 4096 + j) * 2 + 1] = xi[j];
    }
}

// Main conv: 4096-pt complex FFT, 2 real channels packed per block.
__global__ __launch_bounds__(256) void kern_conv4(float* __restrict__ field,
                                                  const float* __restrict__ GBR,
                                                  const float2* __restrict__ twid) {
    __shared__ float2 z[4096];
    const int tid = threadIdx.x;
    const int bh = blockIdx.x >> 6, cp = blockIdx.x & 63;
    float* rowx = field + ((size_t)bh * 128 + 2 * cp) * F_;
    float* rowy = rowx + F_;

    for (int f = tid; f < 2048; f += 256) {
        z[f] = make_float2(rowx[f], rowy[f]);
        z[f + 2048] = make_float2(0.f, 0.f);
    }
    __syncthreads();

    for (int lh = 11; lh >= 0; --lh) {
        const int hh = 1 << lh;
        const float2* tws = twid + lh * 4096;
        for (int t = tid; t < 2048; t += 256) {
            int j = t & (hh - 1);
            int i1 = ((t >> lh) << (lh + 1)) | j;
            int i2 = i1 + hh;
            float2 tw = tws[t];
            float2 a = z[i1], bv = z[i2];
            z[i1] = make_float2(a.x + bv.x, a.y + bv.y);
            float dr = a.x - bv.x, di = a.y - bv.y;
            z[i2] = make_float2(dr * tw.x - di * tw.y, dr * tw.y + di * tw.x);
        }
        __syncthreads();
    }

    {
        const float2* G = (const float2*)(GBR) + (size_t)bh * 4096;
        for (int j = tid; j < 4096; j += 256) {
            float2 g = G[j];
            float2 a = z[j];
            z[j] = make_float2(a.x * g.x - a.y * g.y, a.x * g.y + a.y * g.x);
        }
    }
    __syncthreads();

    for (int lh = 0; lh <= 11; ++lh) {
        const int hh = 1 << lh;
        const float2* tws = twid + lh * 4096;
        for (int t = tid; t < 2048; t += 256) {
            int j = t & (hh - 1);
            int i1 = ((t >> lh) << (lh + 1)) | j;
            int i2 = i1 + hh;
            float2 tw = tws[t];
            float2 bv = z[i2];
            float tr = bv.x * tw.x + bv.y * tw.y;
            float ti = bv.y * tw.x - bv.x * tw.y;
            float2 a = z[i1];
            z[i1] = make_float2(a.x + tr, a.y + ti);
            z[i2] = make_float2(a.x - tr, a.y - ti);
        }
        __syncthreads();
    }

    const float s = 1.f / 4096.f;
    for (int f = tid; f < 2048; f += 256) {
        float2 v = z[f];
        rowx[f] = v.x * s;
        rowy[f] = v.y * s;
    }
}

// head coupling IN PLACE
__global__ __launch_bounds__(256) void kern_coupling(float* __restrict__ field,
                                                     const float* __restrict__ coupling) {
    __shared__ float cp[16][16];
    const int tid = threadIdx.x;
    cp[tid >> 4][tid & 15] = coupling[tid];
    __syncthreads();
    const int f = blockIdx.x * 256 + tid;
    const int c = blockIdx.y;
    const int b = blockIdx.z;
    float val[16];
#pragma unroll
    for (int g = 0; g < 16; ++g)
        val[g] = field[((size_t)(b * 16 + g) * 128 + c) * F_ + f];
    float out[16];
#pragma unroll
    for (int hh = 0; hh < 16; ++hh) {
        float s = 0.f;
#pragma unroll
        for (int g = 0; g < 16; ++g) s += cp[hh][g] * val[g];
        out[hh] = s;
    }
#pragma unroll
    for (int hh = 0; hh < 16; ++hh)
        field[((size_t)(b * 16 + hh) * 128 + c) * F_ + f] = out[hh];
}

// combine -> att written as bf16 hi/lo into qkvg q-columns
// (row r: ushorts [0,1024) = hi, [1024,2048) = lo; exactly the 1024 q floats)
__global__ __launch_bounds__(1024) void kern_combine(float* __restrict__ qkvg,
                                                     const float* __restrict__ field) {
    const int tid = threadIdx.x;
    const int lane = tid & 63, wv = tid >> 6;
    const int n = blockIdx.x * 16 + wv;
    const int h = blockIdx.y, b = blockIdx.z;
    const int f = min(n, F_ - 2);
    const size_t row = (size_t)(b * N_ + n) * 4096;
    float pq = qkvg[row + D_ + h * 64 + lane];
    const float* cv = field + (size_t)(b * H_ + h) * 128 * F_;
    float ynum = cv[(size_t)lane * F_ + f];
    float yden = cv[(size_t)(64 + lane) * F_ + f];
    float gv = qkvg[row + 3 * D_ + h * 64 + lane];
    float s = pq * yden;
    for (int m = 1; m < 64; m <<= 1) s += __shfl_xor(s, m);
    float den = fabsf(s) + 1e-4f;
    float o = pq * ynum / den * (1.f / (1.f + expf(-gv)));
    ushort_t oh, ol;
    split_bf16(o, oh, ol);
    ushort_t* rp = (ushort_t*)(qkvg + row);
    rp[h * 64 + lane] = oh;
    rp[1024 + h * 64 + lane] = ol;
}

// ---------------------------------------------------------------------------
extern "C" void kernel_launch(void* const* d_in, const int* in_sizes, int n_in,
                              void* d_out, int out_size, void* d_ws, size_t ws_size,
                              hipStream_t stream) {
    const float* x      = (const float*)d_in[0];
    const float* w_qkvg = (const float*)d_in[1];
    const float* b_qkvg = (const float*)d_in[2];
    const float* w_out  = (const float*)d_in[3];
    const float* b_out  = (const float*)d_in[4];
    const float* qfm_w  = (const float*)d_in[5];
    const float* qfm_b  = (const float*)d_in[6];
    const float* kfm_w  = (const float*)d_in[7];
    const float* kfm_b  = (const float*)d_in[8];
    const float* wg_w   = (const float*)d_in[9];
    const float* wg_b   = (const float*)d_in[10];
    const float* ln_g   = (const float*)d_in[11];
    const float* ln_b   = (const float*)d_in[12];
    const float* sg_w1  = (const float*)d_in[13];
    const float* sg_b1  = (const float*)d_in[14];
    const float* sg_w2  = (const float*)d_in[15];
    const float* sg_b2  = (const float*)d_in[16];
    const float* wfreq  = (const float*)d_in[17];
    const float* wdamp  = (const float*)d_in[18];
    const float* wphase = (const float*)d_in[19];
    const float* coup   = (const float*)d_in[20];

    float* ws = (float*)d_ws;
    // workspace (floats):
    float*  qkvg   = ws;                 // 33,554,432 (k-cols->phi_q, q-cols->att bf16)
    float*  field  = ws + 33554432;      // 16,777,216 (aliases bf16 staging early)
    float*  baseBR = ws + 50331648;      //    262,144
    float*  GBR    = ws + 50593792;      //    524,288
    float2* twid   = (float2*)(ws + 51118080);  // 106,496 floats
    float*  q0n    = ws + 51224576;      //      4,096
    float*  h1     = ws + 51228672;      //      4,096
    float*  ctrl   = ws + 51232768;      //      2,048
    ushort_t* wouth = (ushort_t*)(ws + 51234816); // 1,048,576 ushorts = 524,288 floats
    ushort_t* woutl = (ushort_t*)(ws + 51759104); // 524,288 floats   (end 52,283,392)

    // bf16 staging aliases inside `field` (consumed by gemm#1 before feat writes)
    ushort_t* xh  = (ushort_t*)(field);             // 8,388,608 ushorts
    ushort_t* xl  = (ushort_t*)(field + 4194304);
    ushort_t* wqh = (ushort_t*)(field + 8388608);   // 4,194,304 ushorts
    ushort_t* wql = (ushort_t*)(field + 10485760);

    // 0. twiddles + splits
    kern_twid8<<<(13 * 4096) / 256, 256, 0, stream>>>(twid);
    kern_split<<<(B_ * N_ * D_) / 256, 256, 0, stream>>>(x, xh, xl, B_ * N_ * D_);
    kern_split<<<(4 * D_ * D_) / 256, 256, 0, stream>>>(w_qkvg, wqh, wql, 4 * D_ * D_);
    kern_split<<<(D_ * D_) / 256, 256, 0, stream>>>(w_out, wouth, woutl, D_ * D_);

    // 1. qkvg = x @ w_qkvg^T + b_qkvg   (split-bf16 MFMA, fp32-accurate)
    gemm_mfma<<<dim3(4096 / 128, 8192 / 128), 256, 0, stream>>>(
        xh, xl, D_, wqh, wql, D_, b_qkvg, qkvg, 4 * D_, D_);

    // 2. control path (reads raw q token 0 before feat overwrites)
    kern_ln<<<B_ * H_, 64, 0, stream>>>(qkvg, ln_g, ln_b, q0n);
    gemm_nt<<<dim3(1024 / 64, 1), 256, 0, stream>>>(q0n, sg_w1, sg_b1, h1, B_, D_, D_, D_, 1);
    gemm_nt<<<dim3(512 / 64, 1), 256, 0, stream>>>(h1, sg_w2, sg_b2, ctrl, B_, H_ * NC_, D_, D_, 0);

    // 3. featmaps + wg + field build (overwrites the bf16 staging aliases - OK)
    kern_feat<<<dim3(N_ / 64, H_, B_), 256, 0, stream>>>(
        qkvg, qfm_w, qfm_b, kfm_w, kfm_b, wg_w, wg_b, field);

    // 4. spectra prep
    kern_base_fft<<<H_, 256, 0, stream>>>(wfreq, wdamp, wphase, twid, baseBR);
    kern_prep<<<B_ * H_, 256, 0, stream>>>(baseBR, ctrl, twid, GBR);

    // 5. FFT convolution (in place on field)
    kern_conv4<<<B_ * H_ * 64, 256, 0, stream>>>(field, GBR, twid);

    // 6. head coupling (in place)
    kern_coupling<<<dim3(F_ / 256, 128, B_), 256, 0, stream>>>(field, coup);

    // 7. combine -> att (bf16 hi/lo) into qkvg q-columns
    kern_combine<<<dim3(N_ / 16, H_, B_), 1024, 0, stream>>>(qkvg, field);

    // 8. out = att @ w_out^T + b_out   (att rows: hi at +0, lo at +1024 ushorts,
    //    row stride 8192 ushorts)
    gemm_mfma<<<dim3(1024 / 128, 8192 / 128), 256, 0, stream>>>(
        (ushort_t*)qkvg, (ushort_t*)qkvg + 1024, 8192,
        wouth, woutl, D_, b_out, (float*)d_out, D_, D_);
}

// Round 6
// 1037.268 us; speedup vs baseline: 2.6939x; 1.0842x over previous
//
#include <hip/hip_runtime.h>
#include <math.h>

// Problem constants
#define B_   4
#define N_   2048
#define D_   1024
#define H_   16
#define d_   64
#define F_   2048
#define PAD_ 8192
#define FB_  4097
#define NC_  32
#define EPS_ 1e-6f
#define PI_F 3.14159265358979323846f
#define PI_D 3.14159265358979323846

typedef unsigned short ushort_t;
typedef short bf16x8 __attribute__((ext_vector_type(8)));
typedef float f32x4  __attribute__((ext_vector_type(4)));

#define GLD16(gp, lp) __builtin_amdgcn_global_load_lds( \
    (const __attribute__((address_space(1))) unsigned int*)(const void*)(gp), \
    (__attribute__((address_space(3))) unsigned int*)(void*)(lp), 16, 0, 0)

// round-to-nearest-even fp32 -> bf16 (bits), plus residual split
__device__ __forceinline__ ushort_t bf16_rne(float v) {
    unsigned b = __float_as_uint(v);
    unsigned rb = b + 0x7fffu + ((b >> 16) & 1u);
    return (ushort_t)(rb >> 16);
}
__device__ __forceinline__ void split_bf16(float v, ushort_t& h, ushort_t& l) {
    h = bf16_rne(v);
    float fh = __uint_as_float((unsigned)h << 16);
    l = bf16_rne(v - fh);
}

__device__ __forceinline__ float2 cmul(float2 a, float2 w) {
    return make_float2(a.x * w.x - a.y * w.y, a.x * w.y + a.y * w.x);
}
__device__ __forceinline__ float2 cmulc(float2 a, float2 w) {   // a * conj(w)
    return make_float2(a.x * w.x + a.y * w.y, a.y * w.x - a.x * w.y);
}

// ---------------------------------------------------------------------------
// kern_split: fp32 array -> (hi, lo) bf16 arrays
// ---------------------------------------------------------------------------
__global__ __launch_bounds__(256) void kern_split(const float* __restrict__ src,
                                                  ushort_t* __restrict__ hi,
                                                  ushort_t* __restrict__ lo, int n) {
    int i = blockIdx.x * 256 + threadIdx.x;
    if (i >= n) return;
    ushort_t h, l;
    split_bf16(src[i], h, l);
    hi[i] = h; lo[i] = l;
}

// ---------------------------------------------------------------------------
// Split-bf16 MFMA NT GEMM: C = A*B^T + bias. 3 cross-products (AlBl dropped:
// contributes <= 2^-18 relative, below fp32 accumulate noise).
// 128x128 tile, BK=32, 256 thr. M, Nn, K multiples of 128.
// ---------------------------------------------------------------------------
__global__ __launch_bounds__(256) void gemm_mfma(
        const ushort_t* __restrict__ Ah, const ushort_t* __restrict__ Al, int lda,
        const ushort_t* __restrict__ Bh, const ushort_t* __restrict__ Bl, int ldb,
        const float* __restrict__ bias, float* __restrict__ C,
        int Nn, int K) {
    __shared__ __align__(16) ushort_t At0[128 * 32];
    __shared__ __align__(16) ushort_t At1[128 * 32];
    __shared__ __align__(16) ushort_t Bt0[128 * 32];
    __shared__ __align__(16) ushort_t Bt1[128 * 32];

    const int tid = threadIdx.x;
    const int wv = tid >> 6, lane = tid & 63;
    const int quad = lane >> 4, lrow = lane & 15;
    const int m0 = blockIdx.y * 128, n0 = blockIdx.x * 128;
    const int mw = (wv >> 1) * 64, nw = (wv & 1) * 64;

    const int srow = lane >> 2;
    const int schunk = (lane & 3) * 8;

    f32x4 acc[4][4] = {};

    for (int k0 = 0; k0 < K; k0 += 32) {
        {
            const size_t ga = (size_t)(m0 + wv * 32 + srow) * lda + k0 + schunk;
            const size_t gb = (size_t)(n0 + wv * 32 + srow) * ldb + k0 + schunk;
            const size_t ga2 = ga + (size_t)16 * lda;
            const size_t gb2 = gb + (size_t)16 * ldb;
            GLD16(Ah + ga,  &At0[(wv * 32) * 32]);
            GLD16(Ah + ga2, &At0[(wv * 32 + 16) * 32]);
            GLD16(Al + ga,  &At1[(wv * 32) * 32]);
            GLD16(Al + ga2, &At1[(wv * 32 + 16) * 32]);
            GLD16(Bh + gb,  &Bt0[(wv * 32) * 32]);
            GLD16(Bh + gb2, &Bt0[(wv * 32 + 16) * 32]);
            GLD16(Bl + gb,  &Bt1[(wv * 32) * 32]);
            GLD16(Bl + gb2, &Bt1[(wv * 32 + 16) * 32]);
        }
        __syncthreads();

        bf16x8 a0[4], a1[4], b0[4], b1[4];
#pragma unroll
        for (int i = 0; i < 4; ++i) {
            a0[i] = *(const bf16x8*)&At0[(mw + i * 16 + lrow) * 32 + quad * 8];
            a1[i] = *(const bf16x8*)&At1[(mw + i * 16 + lrow) * 32 + quad * 8];
            b0[i] = *(const bf16x8*)&Bt0[(nw + i * 16 + lrow) * 32 + quad * 8];
            b1[i] = *(const bf16x8*)&Bt1[(nw + i * 16 + lrow) * 32 + quad * 8];
        }
#pragma unroll
        for (int mi = 0; mi < 4; ++mi)
#pragma unroll
            for (int nj = 0; nj < 4; ++nj) {
                acc[mi][nj] = __builtin_amdgcn_mfma_f32_16x16x32_bf16(a0[mi], b0[nj], acc[mi][nj], 0, 0, 0);
                acc[mi][nj] = __builtin_amdgcn_mfma_f32_16x16x32_bf16(a0[mi], b1[nj], acc[mi][nj], 0, 0, 0);
                acc[mi][nj] = __builtin_amdgcn_mfma_f32_16x16x32_bf16(a1[mi], b0[nj], acc[mi][nj], 0, 0, 0);
            }
        __syncthreads();
    }

#pragma unroll
    for (int mi = 0; mi < 4; ++mi) {
        const int row = m0 + mw + mi * 16 + quad * 4;
#pragma unroll
        for (int nj = 0; nj < 4; ++nj) {
            const int col = n0 + nw + nj * 16 + lrow;
            const float bv = bias[col];
#pragma unroll
            for (int r = 0; r < 4; ++r)
                C[(size_t)(row + r) * Nn + col] = acc[mi][nj][r] + bv;
        }
    }
}

// ---------------------------------------------------------------------------
// Generic fp32 NT GEMM (only the tiny M=4 control GEMMs).
// ---------------------------------------------------------------------------
__device__ __forceinline__ float gelu_f(float x) {
    return 0.5f * x * (1.f + tanhf(0.7978845608028654f * (x + 0.044715f * x * x * x)));
}

__global__ __launch_bounds__(256) void gemm_nt(const float* __restrict__ A,
                                               const float* __restrict__ Bm,
                                               const float* __restrict__ bias,
                                               float* __restrict__ C,
                                               int M, int Nn, int K, int lda, int act) {
    __shared__ float As[16][64];
    __shared__ float Bs[16][64];
    const int tid = threadIdx.x;
    const int tx = tid & 15, ty = tid >> 4;
    const int m0 = blockIdx.y * 64, n0 = blockIdx.x * 64;

    float acc[4][4];
#pragma unroll
    for (int i = 0; i < 4; ++i)
#pragma unroll
        for (int j = 0; j < 4; ++j) acc[i][j] = 0.f;

    const int lr = tid >> 2;
    const int lk = (tid & 3) * 4;

    for (int k0 = 0; k0 < K; k0 += 16) {
        float4 av = make_float4(0.f, 0.f, 0.f, 0.f);
        float4 bv = make_float4(0.f, 0.f, 0.f, 0.f);
        if (m0 + lr < M)
            av = *(const float4*)(A + (size_t)(m0 + lr) * lda + k0 + lk);
        if (n0 + lr < Nn)
            bv = *(const float4*)(Bm + (size_t)(n0 + lr) * K + k0 + lk);
        As[lk + 0][lr] = av.x; As[lk + 1][lr] = av.y;
        As[lk + 2][lr] = av.z; As[lk + 3][lr] = av.w;
        Bs[lk + 0][lr] = bv.x; Bs[lk + 1][lr] = bv.y;
        Bs[lk + 2][lr] = bv.z; Bs[lk + 3][lr] = bv.w;
        __syncthreads();
#pragma unroll
        for (int k = 0; k < 16; ++k) {
            float a[4], b[4];
#pragma unroll
            for (int i = 0; i < 4; ++i) a[i] = As[k][ty * 4 + i];
#pragma unroll
            for (int j = 0; j < 4; ++j) b[j] = Bs[k][tx * 4 + j];
#pragma unroll
            for (int i = 0; i < 4; ++i)
#pragma unroll
                for (int j = 0; j < 4; ++j) acc[i][j] += a[i] * b[j];
        }
        __syncthreads();
    }
#pragma unroll
    for (int i = 0; i < 4; ++i) {
        int row = m0 + ty * 4 + i;
        if (row >= M) continue;
#pragma unroll
        for (int j = 0; j < 4; ++j) {
            int col = n0 + tx * 4 + j;
            if (col >= Nn) continue;
            float v = acc[i][j] + bias[col];
            if (act == 1) v = gelu_f(v);
            C[(size_t)row * Nn + col] = v;
        }
    }
}

// ---------------------------------------------------------------------------
// Featuremap + field build (K path first, then Q path; phi_q -> qkvg k-cols).
// ---------------------------------------------------------------------------
__global__ __launch_bounds__(256) void kern_feat(float* __restrict__ qkvg,
                                                 const float* __restrict__ qfm_w,
                                                 const float* __restrict__ qfm_b,
                                                 const float* __restrict__ kfm_w,
                                                 const float* __restrict__ kfm_b,
                                                 const float* __restrict__ wg_w,
                                                 const float* __restrict__ wg_b,
                                                 float* __restrict__ field) {
    __shared__ float in_t[64][65];
    __shared__ float tmp[64][65];
    __shared__ float wbuf[64][65];
    __shared__ float bsm[64];
    __shared__ float wsm[64];
    __shared__ float wgbuf[64];

    const int tid = threadIdx.x;
    const int lane = tid & 63, grp = tid >> 6;
    const int n0 = blockIdx.x * 64;
    const int h = blockIdx.y, b = blockIdx.z;
    const size_t rowbase = (size_t)(b * N_ + n0) * 4096;

    // ============ K path ============
    for (int it = 0; it < 16; ++it) {
        int i = grp + 4 * it;
        in_t[i][lane] = qkvg[rowbase + (size_t)i * 4096 + D_ + h * 64 + lane];
    }
    for (int it = 0; it < 16; ++it) {
        int r = grp + 4 * it;
        wbuf[lane][r] = kfm_w[(size_t)r * 64 + lane];
    }
    if (tid < 64) { bsm[tid] = kfm_b[tid]; wsm[tid] = wg_w[tid]; }
    __syncthreads();
    if (tid < 64) {
        float s = 0.f;
        for (int c = 0; c < 64; ++c) s += in_t[tid][c] * wsm[c];
        s += wg_b[0];
        wgbuf[tid] = 1.f / (1.f + expf(-s));
    }
    {
        const int j = lane, ibase = grp * 16;
        float acc[16];
#pragma unroll
        for (int ii = 0; ii < 16; ++ii) acc[ii] = 0.f;
        for (int c = 0; c < 64; ++c) {
            float w = wbuf[c][j];
#pragma unroll
            for (int ii = 0; ii < 16; ++ii) acc[ii] += in_t[ibase + ii][c] * w;
        }
        float bj = bsm[j];
#pragma unroll
        for (int ii = 0; ii < 16; ++ii) tmp[ibase + ii][j] = fmaxf(acc[ii] + bj, 0.f);
    }
    __syncthreads();
    for (int it = 0; it < 16; ++it) {
        int r = grp + 4 * it;
        wbuf[lane][r] = kfm_w[(size_t)(64 + r) * 64 + lane];
    }
    if (tid < 64) bsm[tid] = kfm_b[64 + tid];
    __syncthreads();
    {
        const int j = lane, ibase = grp * 16;
        float acc[16];
#pragma unroll
        for (int ii = 0; ii < 16; ++ii) acc[ii] = 0.f;
        for (int c = 0; c < 64; ++c) {
            float w = wbuf[c][j];
#pragma unroll
            for (int ii = 0; ii < 16; ++ii) acc[ii] += tmp[ibase + ii][c] * w;
        }
        float bj = bsm[j];
#pragma unroll
        for (int ii = 0; ii < 16; ++ii)
            in_t[ibase + ii][j] = fmaxf(acc[ii] + bj, 0.f) + EPS_;
    }
    __syncthreads();
    for (int it = 0; it < 16; ++it) {
        int i = grp + 4 * it;
        tmp[i][lane] = qkvg[rowbase + (size_t)i * 4096 + 2 * D_ + h * 64 + lane];
    }
    __syncthreads();

    {
        float* frow = field + (size_t)(b * H_ + h) * 128 * F_;
        const bool last = (n0 == N_ - 64);
        for (int c = grp; c < 128; c += 4) {
            int i = lane;
            float v = (c < 64) ? wgbuf[i] * in_t[i][c] * tmp[i][c]
                               : wgbuf[i] * in_t[i][c - 64];
            if (last) {
                if (i == 62) {
                    float v2 = (c < 64) ? wgbuf[63] * in_t[63][c] * tmp[63][c]
                                        : wgbuf[63] * in_t[63][c - 64];
                    v += v2;
                } else if (i == 63) v = 0.f;
            }
            frow[(size_t)c * F_ + n0 + i] = v;
        }
    }
    __syncthreads();

    // ============ Q path ============
    for (int it = 0; it < 16; ++it) {
        int i = grp + 4 * it;
        in_t[i][lane] = qkvg[rowbase + (size_t)i * 4096 + h * 64 + lane];
    }
    for (int it = 0; it < 16; ++it) {
        int r = grp + 4 * it;
        wbuf[lane][r] = qfm_w[(size_t)r * 64 + lane];
    }
    if (tid < 64) bsm[tid] = qfm_b[tid];
    __syncthreads();
    {
        const int j = lane, ibase = grp * 16;
        float acc[16];
#pragma unroll
        for (int ii = 0; ii < 16; ++ii) acc[ii] = 0.f;
        for (int c = 0; c < 64; ++c) {
            float w = wbuf[c][j];
#pragma unroll
            for (int ii = 0; ii < 16; ++ii) acc[ii] += in_t[ibase + ii][c] * w;
        }
        float bj = bsm[j];
#pragma unroll
        for (int ii = 0; ii < 16; ++ii) tmp[ibase + ii][j] = fmaxf(acc[ii] + bj, 0.f);
    }
    __syncthreads();
    for (int it = 0; it < 16; ++it) {
        int r = grp + 4 * it;
        wbuf[lane][r] = qfm_w[(size_t)(64 + r) * 64 + lane];
    }
    if (tid < 64) bsm[tid] = qfm_b[64 + tid];
    __syncthreads();
    {
        const int j = lane, ibase = grp * 16;
        float acc[16];
#pragma unroll
        for (int ii = 0; ii < 16; ++ii) acc[ii] = 0.f;
        for (int c = 0; c < 64; ++c) {
            float w = wbuf[c][j];
#pragma unroll
            for (int ii = 0; ii < 16; ++ii) acc[ii] += tmp[ibase + ii][c] * w;
        }
        float bj = bsm[j];
#pragma unroll
        for (int ii = 0; ii < 16; ++ii) {
            float v = fmaxf(acc[ii] + bj, 0.f) + EPS_;
            qkvg[rowbase + (size_t)(ibase + ii) * 4096 + D_ + h * 64 + j] = v;
        }
    }
}

// ---------------------------------------------------------------------------
// LayerNorm of q token 0 -> q0n (B x 1024).
// ---------------------------------------------------------------------------
__global__ void kern_ln(const float* __restrict__ qkvg,
                        const float* __restrict__ ln_g,
                        const float* __restrict__ ln_b,
                        float* __restrict__ q0n) {
    const int bh = blockIdx.x, c = threadIdx.x;
    const int b = bh >> 4, h = bh & 15;
    float x = qkvg[(size_t)(b * N_) * 4096 + h * 64 + c];
    float mu = x;
    for (int m = 1; m < 64; m <<= 1) mu += __shfl_xor(mu, m);
    mu *= (1.f / 64.f);
    float dv = (x - mu) * (x - mu);
    for (int m = 1; m < 64; m <<= 1) dv += __shfl_xor(dv, m);
    float var = dv * (1.f / 64.f);
    q0n[b * 1024 + h * 64 + c] = (x - mu) * rsqrtf(var + 1e-5f) * ln_g[c] + ln_b[c];
}

// ---------------------------------------------------------------------------
// Radix-2 twiddles (8192-pt transforms): twid[lh*4096+t] = exp(-i*pi*(t&(hh-1))/hh)
// ---------------------------------------------------------------------------
__global__ __launch_bounds__(256) void kern_twid8(float2* __restrict__ twid) {
    const int idx = blockIdx.x * 256 + threadIdx.x;
    const int lh = idx >> 12, t = idx & 4095;
    const int hh = 1 << lh;
    const int j = t & (hh - 1);
    double s, c;
    sincos(-PI_D * (double)j / (double)hh, &s, &c);
    twid[idx] = make_float2((float)c, (float)s);
}

// Radix-4 twiddles (4096-pt): tw4[s*3072 + 3*j + (m-1)] = exp(-2pi*i*m*j/(4*q_s)),
// q_s = 1024 >> (2s), s in [0,6), m in {1,2,3}, j in [0,1024).
__global__ __launch_bounds__(256) void kern_twid4(float2* __restrict__ tw4) {
    const int idx = blockIdx.x * 256 + threadIdx.x;   // 6*3072
    const int s = idx / 3072;
    const int r = idx - s * 3072;
    const int j = r / 3;
    const int m = r - 3 * j + 1;
    const int q = 1024 >> (2 * s);
    double sn, cs;
    sincos(-2.0 * PI_D * (double)(m * (j & (q - 1))) / (double)(4 * q), &sn, &cs);
    tw4[idx] = make_float2((float)cs, (float)sn);
}

// ---------------------------------------------------------------------------
// Radix-2 table-driven FFT helpers (8192-pt path only).
// ---------------------------------------------------------------------------
__device__ __forceinline__ void fft_fwd_dif_t(float* xr, float* xi, int tid, int logn,
                                              const float2* __restrict__ twid) {
    const int nb = 1 << (logn - 1);
    for (int lh = logn - 1; lh >= 0; --lh) {
        const int hh = 1 << lh;
        const float2* tws = twid + lh * 4096;
        for (int t = tid; t < nb; t += 256) {
            int j = t & (hh - 1);
            int i1 = ((t >> lh) << (lh + 1)) | j;
            int i2 = i1 + hh;
            float2 tw = tws[t];
            float ar = xr[i1], ai = xi[i1];
            float br = xr[i2], bi = xi[i2];
            xr[i1] = ar + br; xi[i1] = ai + bi;
            float tr = ar - br, ti = ai - bi;
            xr[i2] = tr * tw.x - ti * tw.y;
            xi[i2] = tr * tw.y + ti * tw.x;
        }
        __syncthreads();
    }
}

__device__ __forceinline__ void fft_inv_dit_t(float* xr, float* xi, int tid, int logn,
                                              const float2* __restrict__ twid) {
    const int nb = 1 << (logn - 1);
    for (int lh = 0; lh < logn; ++lh) {
        const int hh = 1 << lh;
        const float2* tws = twid + lh * 4096;
        for (int t = tid; t < nb; t += 256) {
            int j = t & (hh - 1);
            int i1 = ((t >> lh) << (lh + 1)) | j;
            int i2 = i1 + hh;
            float2 tw = tws[t];
            float br = xr[i2], bi = xi[i2];
            float tr = br * tw.x + bi * tw.y;
            float ti = bi * tw.x - br * tw.y;
            float ar = xr[i1], ai = xi[i1];
            xr[i1] = ar + tr; xi[i1] = ai + ti;
            xr[i2] = ar - tr; xi[i2] = ai - ti;
        }
        __syncthreads();
    }
}

// ---------------------------------------------------------------------------
// Radix-4 4096-pt FFT on float2 LDS. Fwd: natural -> base-4 digit-reversed.
// Inv: digit-reversed -> natural (conj twiddles). 6 stages each.
// ---------------------------------------------------------------------------
__device__ __forceinline__ void fft4_fwd(float2* z, int tid,
                                         const float2* __restrict__ tw4) {
#pragma unroll
    for (int s = 0; s < 6; ++s) {
        const int q = 1024 >> (2 * s);
        const float2* tws = tw4 + s * 3072;
#pragma unroll
        for (int u = 0; u < 4; ++u) {
            int t = tid + u * 256;
            int j = t & (q - 1);
            int base = ((t & ~(q - 1)) << 2) | j;
            float2 a = z[base], b = z[base + q], c = z[base + 2 * q], d = z[base + 3 * q];
            float2 s0 = make_float2(a.x + c.x, a.y + c.y);
            float2 s1 = make_float2(a.x - c.x, a.y - c.y);
            float2 s2 = make_float2(b.x + d.x, b.y + d.y);
            float2 s3 = make_float2(b.x - d.x, b.y - d.y);
            float2 m1 = make_float2(s1.x + s3.y, s1.y - s3.x);   // s1 - i*s3
            float2 m2 = make_float2(s0.x - s2.x, s0.y - s2.y);
            float2 m3 = make_float2(s1.x - s3.y, s1.y + s3.x);   // s1 + i*s3
            z[base]         = make_float2(s0.x + s2.x, s0.y + s2.y);
            z[base + q]     = cmul(m1, tws[3 * j + 0]);
            z[base + 2 * q] = cmul(m2, tws[3 * j + 1]);
            z[base + 3 * q] = cmul(m3, tws[3 * j + 2]);
        }
        __syncthreads();
    }
}

__device__ __forceinline__ void fft4_inv(float2* z, int tid,
                                         const float2* __restrict__ tw4) {
#pragma unroll
    for (int s = 5; s >= 0; --s) {
        const int q = 1024 >> (2 * s);
        const float2* tws = tw4 + s * 3072;
#pragma unroll
        for (int u = 0; u < 4; ++u) {
            int t = tid + u * 256;
            int j = t & (q - 1);
            int base = ((t & ~(q - 1)) << 2) | j;
            float2 a = z[base];
            float2 b = cmulc(z[base + q],     tws[3 * j + 0]);
            float2 c = cmulc(z[base + 2 * q], tws[3 * j + 1]);
            float2 d = cmulc(z[base + 3 * q], tws[3 * j + 2]);
            float2 p0 = make_float2(a.x + c.x, a.y + c.y);
            float2 p1 = make_float2(a.x - c.x, a.y - c.y);
            float2 p2 = make_float2(b.x + d.x, b.y + d.y);
            float2 p3 = make_float2(b.x - d.x, b.y - d.y);
            z[base]         = make_float2(p0.x + p2.x, p0.y + p2.y);
            z[base + q]     = make_float2(p1.x - p3.y, p1.y + p3.x);   // p1 + i*p3
            z[base + 2 * q] = make_float2(p0.x - p2.x, p0.y - p2.y);
            z[base + 3 * q] = make_float2(p1.x + p3.y, p1.y - p3.x);   // p1 - i*p3
        }
        __syncthreads();
    }
}

// base spectrum (radix-2 BR order, 8192-pt) of the damped-cosine kernel
__global__ __launch_bounds__(256) void kern_base_fft(const float* __restrict__ freq,
                                                     const float* __restrict__ damp,
                                                     const float* __restrict__ phase,
                                                     const float2* __restrict__ twid,
                                                     float* __restrict__ baseBR) {
    __shared__ float xr[PAD_];
    __shared__ float xi[PAD_];
    const int h = blockIdx.x, tid = threadIdx.x;
    const float fr = freq[h], ed = expf(damp[h]), ph = phase[h];
    for (int f = tid; f < PAD_; f += 256) {
        float v = 0.f;
        if (f < F_) {
            float t = (float)f / (float)F_;
            v = expf(-ed * t) * cosf(fr * t + ph);
        }
        xr[f] = v; xi[f] = 0.f;
    }
    __syncthreads();
    fft_fwd_dif_t(xr, xi, tid, 13, twid);
    for (int j = tid; j < PAD_; j += 256) {
        baseBR[(size_t)(h * PAD_ + j) * 2 + 0] = xr[j];
        baseBR[(size_t)(h * PAD_ + j) * 2 + 1] = xi[j];
    }
}

// Per (b,h): mod spectrum (8192 BR) -> keff -> fold to 4096 -> radix-4 fwd -> GBR
// (GBR in base-4 digit-reversed order, matching kern_conv4's forward)
__global__ __launch_bounds__(256) void kern_prep(const float* __restrict__ baseBR,
                                                 const float* __restrict__ ctrl,
                                                 const float2* __restrict__ twid,
                                                 const float2* __restrict__ tw4,
                                                 float* __restrict__ GBR) {
    __shared__ float sm[2 * PAD_];    // 64 KB: xr=sm[0..8192), xi=sm[8192..16384)
    float* xr = sm;
    float* xi = sm + PAD_;
    const int bh = blockIdx.x, tid = threadIdx.x;
    const int b = bh >> 4, h = bh & 15;
    const float* cp = ctrl + b * (H_ * NC_) + h * NC_;
    for (int j = tid; j < PAD_; j += 256) {
        int k = (int)(__brev((unsigned)j) >> 19);
        int kk = min(k, PAD_ - k);
        float ip = (float)kk * ((float)(NC_ - 1) / (float)(FB_ - 1));
        int il = min((int)ip, NC_ - 2);
        float iw = ip - (float)il;
        float m = 1.f + cp[il] * (1.f - iw) + cp[il + 1] * iw;
        xr[j] = baseBR[(size_t)(h * PAD_ + j) * 2 + 0] * m;
        xi[j] = baseBR[(size_t)(h * PAD_ + j) * 2 + 1] * m;
    }
    __syncthreads();
    fft_inv_dit_t(xr, xi, tid, 13, twid);   // BR -> natural keff (unscaled)

    // fold to 4096 real kernel, staged through registers (z aliases xr/xi memory)
    float g[16];
    const float sc = 1.f / (float)PAD_;
#pragma unroll
    for (int u = 0; u < 16; ++u) {
        int j = tid + u * 256;
        g[u] = ((j < 2048) ? xr[j] : xr[j + 4096]) * sc;
    }
    __syncthreads();
    float2* z = (float2*)sm;
#pragma unroll
    for (int u = 0; u < 16; ++u) {
        int j = tid + u * 256;
        z[j] = make_float2(g[u], 0.f);
    }
    __syncthreads();
    fft4_fwd(z, tid, tw4);                  // natural -> digit-reversed
    for (int j = tid; j < 4096; j += 256) {
        GBR[((size_t)bh * 4096 + j) * 2 + 0] = z[j].x;
        GBR[((size_t)bh * 4096 + j) * 2 + 1] = z[j].y;
    }
}

// Main conv: 4096-pt radix-4 complex FFT, 2 real channels packed per block.
__global__ __launch_bounds__(256) void kern_conv4(float* __restrict__ field,
                                                  const float* __restrict__ GBR,
                                                  const float2* __restrict__ tw4) {
    __shared__ float2 z[4096];
    const int tid = threadIdx.x;
    const int bh = blockIdx.x >> 6, cp = blockIdx.x & 63;
    float* rowx = field + ((size_t)bh * 128 + 2 * cp) * F_;
    float* rowy = rowx + F_;

    for (int f = tid; f < 2048; f += 256) {
        z[f] = make_float2(rowx[f], rowy[f]);
        z[f + 2048] = make_float2(0.f, 0.f);
    }
    __syncthreads();

    fft4_fwd(z, tid, tw4);

    {
        const float2* G = (const float2*)(GBR) + (size_t)bh * 4096;
        for (int j = tid; j < 4096; j += 256)
            z[j] = cmul(z[j], G[j]);
    }
    __syncthreads();

    fft4_inv(z, tid, tw4);

    const float s = 1.f / 4096.f;
    for (int f = tid; f < 2048; f += 256) {
        float2 v = z[f];
        rowx[f] = v.x * s;
        rowy[f] = v.y * s;
    }
}

// head coupling IN PLACE
__global__ __launch_bounds__(256) void kern_coupling(float* __restrict__ field,
                                                     const float* __restrict__ coupling) {
    __shared__ float cp[16][16];
    const int tid = threadIdx.x;
    cp[tid >> 4][tid & 15] = coupling[tid];
    __syncthreads();
    const int f = blockIdx.x * 256 + tid;
    const int c = blockIdx.y;
    const int b = blockIdx.z;
    float val[16];
#pragma unroll
    for (int g = 0; g < 16; ++g)
        val[g] = field[((size_t)(b * 16 + g) * 128 + c) * F_ + f];
    float out[16];
#pragma unroll
    for (int hh = 0; hh < 16; ++hh) {
        float s = 0.f;
#pragma unroll
        for (int g = 0; g < 16; ++g) s += cp[hh][g] * val[g];
        out[hh] = s;
    }
#pragma unroll
    for (int hh = 0; hh < 16; ++hh)
        field[((size_t)(b * 16 + hh) * 128 + c) * F_ + f] = out[hh];
}

// combine -> att written as bf16 hi/lo into qkvg q-columns
__global__ __launch_bounds__(1024) void kern_combine(float* __restrict__ qkvg,
                                                     const float* __restrict__ field) {
    const int tid = threadIdx.x;
    const int lane = tid & 63, wv = tid >> 6;
    const int n = blockIdx.x * 16 + wv;
    const int h = blockIdx.y, b = blockIdx.z;
    const int f = min(n, F_ - 2);
    const size_t row = (size_t)(b * N_ + n) * 4096;
    float pq = qkvg[row + D_ + h * 64 + lane];
    const float* cv = field + (size_t)(b * H_ + h) * 128 * F_;
    float ynum = cv[(size_t)lane * F_ + f];
    float yden = cv[(size_t)(64 + lane) * F_ + f];
    float gv = qkvg[row + 3 * D_ + h * 64 + lane];
    float s = pq * yden;
    for (int m = 1; m < 64; m <<= 1) s += __shfl_xor(s, m);
    float den = fabsf(s) + 1e-4f;
    float o = pq * ynum / den * (1.f / (1.f + expf(-gv)));
    ushort_t oh, ol;
    split_bf16(o, oh, ol);
    ushort_t* rp = (ushort_t*)(qkvg + row);
    rp[h * 64 + lane] = oh;
    rp[1024 + h * 64 + lane] = ol;
}

// ---------------------------------------------------------------------------
extern "C" void kernel_launch(void* const* d_in, const int* in_sizes, int n_in,
                              void* d_out, int out_size, void* d_ws, size_t ws_size,
                              hipStream_t stream) {
    const float* x      = (const float*)d_in[0];
    const float* w_qkvg = (const float*)d_in[1];
    const float* b_qkvg = (const float*)d_in[2];
    const float* w_out  = (const float*)d_in[3];
    const float* b_out  = (const float*)d_in[4];
    const float* qfm_w  = (const float*)d_in[5];
    const float* qfm_b  = (const float*)d_in[6];
    const float* kfm_w  = (const float*)d_in[7];
    const float* kfm_b  = (const float*)d_in[8];
    const float* wg_w   = (const float*)d_in[9];
    const float* wg_b   = (const float*)d_in[10];
    const float* ln_g   = (const float*)d_in[11];
    const float* ln_b   = (const float*)d_in[12];
    const float* sg_w1  = (const float*)d_in[13];
    const float* sg_b1  = (const float*)d_in[14];
    const float* sg_w2  = (const float*)d_in[15];
    const float* sg_b2  = (const float*)d_in[16];
    const float* wfreq  = (const float*)d_in[17];
    const float* wdamp  = (const float*)d_in[18];
    const float* wphase = (const float*)d_in[19];
    const float* coup   = (const float*)d_in[20];

    float* ws = (float*)d_ws;
    // workspace (floats):
    float*  qkvg   = ws;                 // 33,554,432
    float*  field  = ws + 33554432;      // 16,777,216
    float*  baseBR = ws + 50331648;      //    262,144
    float*  GBR    = ws + 50593792;      //    524,288
    float2* twid   = (float2*)(ws + 51118080);   // 106,496 floats (radix-2)
    float*  q0n    = ws + 51224576;      //      4,096
    float*  h1     = ws + 51228672;      //      4,096
    float*  ctrl   = ws + 51232768;      //      2,048
    ushort_t* wouth = (ushort_t*)(ws + 51234816); // 524,288 floats
    ushort_t* woutl = (ushort_t*)(ws + 51759104); // 524,288 floats
    float2* tw4    = (float2*)(ws + 52283392);    // 36,864 floats (radix-4)
    // end: 52,320,256 floats = 209.3 MB

    // bf16 staging aliases inside `field` (consumed by gemm#1 before feat writes)
    ushort_t* xh  = (ushort_t*)(field);
    ushort_t* xl  = (ushort_t*)(field + 4194304);
    ushort_t* wqh = (ushort_t*)(field + 8388608);
    ushort_t* wql = (ushort_t*)(field + 10485760);

    // 0. twiddles + splits
    kern_twid8<<<(13 * 4096) / 256, 256, 0, stream>>>(twid);
    kern_twid4<<<(6 * 3072) / 256, 256, 0, stream>>>(tw4);
    kern_split<<<(B_ * N_ * D_) / 256, 256, 0, stream>>>(x, xh, xl, B_ * N_ * D_);
    kern_split<<<(4 * D_ * D_) / 256, 256, 0, stream>>>(w_qkvg, wqh, wql, 4 * D_ * D_);
    kern_split<<<(D_ * D_) / 256, 256, 0, stream>>>(w_out, wouth, woutl, D_ * D_);

    // 1. qkvg = x @ w_qkvg^T + b_qkvg   (split-bf16 MFMA)
    gemm_mfma<<<dim3(4096 / 128, 8192 / 128), 256, 0, stream>>>(
        xh, xl, D_, wqh, wql, D_, b_qkvg, qkvg, 4 * D_, D_);

    // 2. control path
    kern_ln<<<B_ * H_, 64, 0, stream>>>(qkvg, ln_g, ln_b, q0n);
    gemm_nt<<<dim3(1024 / 64, 1), 256, 0, stream>>>(q0n, sg_w1, sg_b1, h1, B_, D_, D_, D_, 1);
    gemm_nt<<<dim3(512 / 64, 1), 256, 0, stream>>>(h1, sg_w2, sg_b2, ctrl, B_, H_ * NC_, D_, D_, 0);

    // 3. featmaps + wg + field build
    kern_feat<<<dim3(N_ / 64, H_, B_), 256, 0, stream>>>(
        qkvg, qfm_w, qfm_b, kfm_w, kfm_b, wg_w, wg_b, field);

    // 4. spectra prep
    kern_base_fft<<<H_, 256, 0, stream>>>(wfreq, wdamp, wphase, twid, baseBR);
    kern_prep<<<B_ * H_, 256, 0, stream>>>(baseBR, ctrl, twid, tw4, GBR);

    // 5. FFT convolution (radix-4, in place on field)
    kern_conv4<<<B_ * H_ * 64, 256, 0, stream>>>(field, GBR, tw4);

    // 6. head coupling (in place)
    kern_coupling<<<dim3(F_ / 256, 128, B_), 256, 0, stream>>>(field, coup);

    // 7. combine -> att (bf16 hi/lo) into qkvg q-columns
    kern_combine<<<dim3(N_ / 16, H_, B_), 1024, 0, stream>>>(qkvg, field);

    // 8. out = att @ w_out^T + b_out
    gemm_mfma<<<dim3(1024 / 128, 8192 / 128), 256, 0, stream>>>(
        (ushort_t*)qkvg, (ushort_t*)qkvg + 1024, 8192,
        wouth, woutl, D_, b_out, (float*)d_out, D_, D_);
}